// Round 19
// baseline (337.690 us; speedup 1.0000x reference)
//
#include <hip/hip_runtime.h>
#include <hip/hip_bf16.h>

#define NN   50000
#define EE   600000
#define DINK 518
#define KP1  576          // padded K for encoder GEMM1 (9*64)
#define MP   50048        // padded rows (391*128)
#define DD   128
#define NEG_SLOPE 0.2f

typedef short bf16x8 __attribute__((ext_vector_type(8)));
typedef float f32x4 __attribute__((ext_vector_type(4)));

typedef const __attribute__((address_space(1))) void* gp1_t;
typedef __attribute__((address_space(3))) void* lp3_t;

__device__ __forceinline__ void load_lds16(const void* g, void* l) {
  __builtin_amdgcn_global_load_lds((gp1_t)g, (lp3_t)l, 16, 0, 0);
}

__device__ __forceinline__ unsigned short f2bf(float f) {
  union { float f; unsigned u; } q; q.f = f;
  unsigned u = q.u + 0x7FFFu + ((q.u >> 16) & 1u);   // RNE
  return (unsigned short)(u >> 16);
}
__device__ __forceinline__ float bflo(unsigned u) {
  union { unsigned u; float f; } q; q.u = u << 16; return q.f;
}
__device__ __forceinline__ float bfhi(unsigned u) {
  union { unsigned u; float f; } q; q.u = u & 0xFFFF0000u; return q.f;
}

// ---------------- bf16 MFMA GEMM:  C = act(A @ BT^T [+ bias]) ----------------
// A:[Mpad][K] bf16 row-major; BT:[Ncols][K] bf16. 128x128 tile, BK=64, 4 waves.
// DOTS (bn==0, Ncols==128): also emit ssrc/sdst = (C row).att_{src,dst}
// from the fp32 accumulators (+bias when HASBIAS) — replaces sdots kernel.
template<bool OUT_BF16, bool RELU, bool HASBIAS, bool DOTS>
__global__ __launch_bounds__(256) void gemm_mfma(
    const unsigned short* __restrict__ A, const unsigned short* __restrict__ BT,
    const float* __restrict__ bias, void* __restrict__ Cout,
    int M, int Ncols, int K,
    const float* __restrict__ att_src, const float* __restrict__ att_dst,
    float* __restrict__ ssrc, float* __restrict__ sdst) {
  __shared__ short As[128][64];
  __shared__ short Bs[128][64];
  __shared__ float sp[128], dp[128];
  const int tid = threadIdx.x;
  const int lane = tid & 63;
  const int wid = tid >> 6;
  const int wr = wid >> 1, wc = wid & 1;
  const int bm = blockIdx.x * 128;
  const int bn = blockIdx.y * 128;
  const int ar = tid >> 3;
  const int ac = (tid & 7) * 8;

  f32x4 acc[4][4] = {};

  for (int k0 = 0; k0 < K; k0 += 64) {
#pragma unroll
    for (int i = 0; i < 4; i++)
      load_lds16(A + (size_t)(bm + ar + i * 32) * K + k0 + ac, &As[ar + i * 32][ac]);
#pragma unroll
    for (int i = 0; i < 4; i++)
      load_lds16(BT + (size_t)(bn + ar + i * 32) * K + k0 + ac, &Bs[ar + i * 32][ac]);
    __syncthreads();
#pragma unroll
    for (int ks = 0; ks < 2; ks++) {
      bf16x8 af[4], bfm[4];
#pragma unroll
      for (int f = 0; f < 4; f++)
        af[f] = *(const bf16x8*)&As[wr * 64 + f * 16 + (lane & 15)][ks * 32 + (lane >> 4) * 8];
#pragma unroll
      for (int f = 0; f < 4; f++)
        bfm[f] = *(const bf16x8*)&Bs[wc * 64 + f * 16 + (lane & 15)][ks * 32 + (lane >> 4) * 8];
#pragma unroll
      for (int i = 0; i < 4; i++)
#pragma unroll
        for (int j = 0; j < 4; j++)
          acc[i][j] = __builtin_amdgcn_mfma_f32_16x16x32_bf16(af[i], bfm[j], acc[i][j], 0, 0, 0);
    }
    __syncthreads();
  }

  // C/D layout (m89/m91): col = lane&15, row = (lane>>4)*4 + reg
  const int col0 = bn + wc * 64 + (lane & 15);
  const int row0 = bm + wr * 64 + (lane >> 4) * 4;
#pragma unroll
  for (int i = 0; i < 4; i++) {
#pragma unroll
    for (int jf = 0; jf < 4; jf++) {
      int col = col0 + jf * 16;
      float bv = HASBIAS ? bias[col] : 0.f;
#pragma unroll
      for (int j = 0; j < 4; j++) {
        int row = row0 + i * 16 + j;
        if (row < M) {
          float v = acc[i][jf][j] + bv;
          if (RELU) v = fmaxf(v, 0.f);
          if (OUT_BF16)
            ((unsigned short*)Cout)[(size_t)row * Ncols + col] = f2bf(v);
          else
            ((float*)Cout)[(size_t)row * Ncols + col] = v;
        }
      }
    }
  }

  if (DOTS) {
    float as_[4], ad_[4], bv_[4];
#pragma unroll
    for (int jf = 0; jf < 4; jf++) {
      int col = col0 + jf * 16;           // bn==0, covers 0..127 across wc
      as_[jf] = att_src[col];
      ad_[jf] = att_dst[col];
      bv_[jf] = HASBIAS ? bias[col] : 0.f;
    }
    float ps[4][4], pd[4][4];
#pragma unroll
    for (int i = 0; i < 4; i++) {
#pragma unroll
      for (int j = 0; j < 4; j++) {
        float s = 0.f, d = 0.f;
#pragma unroll
        for (int jf = 0; jf < 4; jf++) {
          float vv = acc[i][jf][j] + bv_[jf];
          s += vv * as_[jf];
          d += vv * ad_[jf];
        }
#pragma unroll
        for (int off = 1; off < 16; off <<= 1) {   // butterfly over lane&15 (cols)
          s += __shfl_xor(s, off);
          d += __shfl_xor(d, off);
        }
        ps[i][j] = s; pd[i][j] = d;
      }
    }
    // cross-wave (wc) combine via LDS; local row = wr*64 + i*16 + (lane>>4)*4 + j
    if (wc == 0 && (lane & 15) == 0) {
#pragma unroll
      for (int i = 0; i < 4; i++)
#pragma unroll
        for (int j = 0; j < 4; j++) {
          int r = wr * 64 + i * 16 + (lane >> 4) * 4 + j;
          sp[r] = ps[i][j]; dp[r] = pd[i][j];
        }
    }
    __syncthreads();
    if (wc == 1 && (lane & 15) == 0) {
#pragma unroll
      for (int i = 0; i < 4; i++)
#pragma unroll
        for (int j = 0; j < 4; j++) {
          int r = wr * 64 + i * 16 + (lane >> 4) * 4 + j;
          sp[r] += ps[i][j]; dp[r] += pd[i][j];
        }
    }
    __syncthreads();
    if (tid < 128) {
      int gr = bm + tid;
      if (gr < M) { ssrc[gr] = sp[tid]; sdst[gr] = dp[tid]; }
    }
  }
}

// ---------------- GEMM1 with fused fp32->bf16 A conversion ----------------
// Round-13 proven config (72us, 35% occ): BM=64/BN=128, two-phase staging.
__global__ __launch_bounds__(256) void gemm1_fused(
    const float* __restrict__ x, const unsigned short* __restrict__ BT,
    const float* __restrict__ bias, unsigned short* __restrict__ Cout) {
  __shared__ short As[64][64];
  __shared__ short Bs[128][64];
  const int tid = threadIdx.x;
  const int lane = tid & 63;
  const int wid = tid >> 6;             // wave id = column-tile owner
  const int bm = blockIdx.x * 64;
  const int bn = blockIdx.y * 128;
  const int br = tid >> 3;              // B loader row 0..31
  const int bc = (tid & 7) * 8;
  const int rlane = lane >> 5;          // 0/1: which of the 2 rows per instr
  const int klane = (lane & 31) * 2;    // k-offset 0..62

  f32x4 acc[4][2] = {};

  for (int k0 = 0; k0 < KP1; k0 += 64) {
#pragma unroll
    for (int i = 0; i < 4; i++)
      load_lds16(BT + (size_t)(bn + br + i * 32) * KP1 + k0 + bc, &Bs[br + i * 32][bc]);
    // phase 1: issue all A loads (statically indexed -> registers)
    float2 v[8];
    const int kk = k0 + klane;
    const bool kok = (kk < DINK);
#pragma unroll
    for (int i = 0; i < 8; i++) {
      int grow = bm + wid * 16 + i * 2 + rlane;
      v[i] = make_float2(0.f, 0.f);
      if (kok && grow < NN) v[i] = *(const float2*)&x[(size_t)grow * DINK + kk];
    }
    // phase 2: convert + LDS write
#pragma unroll
    for (int i = 0; i < 8; i++) {
      int rl = wid * 16 + i * 2 + rlane;
      unsigned pk;
      asm("v_cvt_pk_bf16_f32 %0, %1, %2" : "=v"(pk) : "v"(v[i].x), "v"(v[i].y));
      *(unsigned*)&As[rl][klane] = pk;
    }
    __syncthreads();
#pragma unroll
    for (int ks = 0; ks < 2; ks++) {
      bf16x8 af[4], bfm[2];
#pragma unroll
      for (int f = 0; f < 4; f++)
        af[f] = *(const bf16x8*)&As[f * 16 + (lane & 15)][ks * 32 + (lane >> 4) * 8];
#pragma unroll
      for (int f = 0; f < 2; f++)
        bfm[f] = *(const bf16x8*)&Bs[wid * 32 + f * 16 + (lane & 15)][ks * 32 + (lane >> 4) * 8];
#pragma unroll
      for (int i = 0; i < 4; i++)
#pragma unroll
        for (int j = 0; j < 2; j++)
          acc[i][j] = __builtin_amdgcn_mfma_f32_16x16x32_bf16(af[i], bfm[j], acc[i][j], 0, 0, 0);
    }
    __syncthreads();
  }

  const int col0 = bn + wid * 32 + (lane & 15);
  const int row0 = bm + (lane >> 4) * 4;
#pragma unroll
  for (int i = 0; i < 4; i++) {
#pragma unroll
    for (int jf = 0; jf < 2; jf++) {
      int col = col0 + jf * 16;
      float bv = bias[col];
#pragma unroll
      for (int j = 0; j < 4; j++) {
        int row = row0 + i * 16 + j;
        if (row < NN) {
          float v2 = fmaxf(acc[i][jf][j] + bv, 0.f);
          Cout[(size_t)row * 256 + col] = f2bf(v2);
        }
      }
    }
  }
}

// -------- combined weight prep: W1T, l2T, tables, and W2L1 = W2@lin1 --------
__device__ __forceinline__ void convT_body(const float* __restrict__ W,
                                           unsigned short* __restrict__ WT,
                                           int K, int Ncols, int Kpad, int t) {
  int n = t / Kpad, k = t % Kpad;
  float v = (k < K) ? W[(size_t)k * Ncols + n] : 0.f;
  WT[(size_t)n * Kpad + k] = f2bf(v);
}

__global__ __launch_bounds__(256) void prep_kernel(
    const float* __restrict__ W1, const float* __restrict__ W2,
    const float* __restrict__ l1, const float* __restrict__ l2,
    const float* __restrict__ le1, const float* __restrict__ le2,
    const float* __restrict__ ae1, const float* __restrict__ ae2,
    const float* __restrict__ rel_emb, const float* __restrict__ b2,
    unsigned short* __restrict__ W1T, unsigned short* __restrict__ W2L1T,
    unsigned short* __restrict__ l2T, float* __restrict__ tables,
    float* __restrict__ b2l1) {
  const int b = blockIdx.x, tid = threadIdx.x;
  if (b < 576) { convT_body(W1, W1T, DINK, 256, KP1, b * 256 + tid); return; }
  if (b < 640) { convT_body(l2, l2T, 128, 128, 128, (b - 576) * 256 + tid); return; }
  if (b < 642) {
    // tables[layer][r] = rel_emb[r] . (line @ att_edge)
    const int layer = b - 640;
    const float* line = layer ? le2 : le1;
    const float* ae   = layer ? ae2 : ae1;
    __shared__ float ve[32];
    if (tid < 32) {
      float s = 0.f;
      for (int d = 0; d < 128; d++) s += line[tid * 128 + d] * ae[d];
      ve[tid] = s;
    }
    __syncthreads();
    if (tid < 26) {
      float s = 0.f;
      for (int j = 0; j < 32; j++) s += rel_emb[tid * 32 + j] * ve[j];
      tables[layer * 32 + tid] = s;
    }
    return;
  }
  // W2L1T[n][k] = sum_j W2[k][j]*lin1[j][n]  (n = output col, k = 0..255)
  const int n = b - 642;
  __shared__ float lc[128];
  if (tid < 128) lc[tid] = l1[(size_t)tid * 128 + n];
  __syncthreads();
  float s = 0.f;
  const float* wrow = W2 + (size_t)tid * 128;
  for (int j = 0; j < 128; j++) s += wrow[j] * lc[j];
  W2L1T[(size_t)n * 256 + tid] = f2bf(s);
  if (tid == 0) {
    float bb = 0.f;
    for (int j = 0; j < 128; j++) bb += b2[j] * lc[j];
    b2l1[n] = bb;
  }
}

// ---------------- CSR build (counting sort by dst; reused by both layers) ----
__global__ void cnti_kernel(const int* __restrict__ dst, int* __restrict__ cnti, int E) {
  int e = blockIdx.x * blockDim.x + threadIdx.x;
  if (e < E) atomicAdd(&cnti[dst[e]], 1);
}

__global__ void partial_kernel(const int* __restrict__ cnti, int* __restrict__ partial, int n) {
  __shared__ int sh[4];
  int i = blockIdx.x * 256 + threadIdx.x;
  int lane = threadIdx.x & 63, wid = threadIdx.x >> 6;
  int v = (i < n) ? cnti[i] : 0;
#pragma unroll
  for (int off = 32; off; off >>= 1) v += __shfl_xor(v, off);
  if (lane == 0) sh[wid] = v;
  __syncthreads();
  if (threadIdx.x == 0) partial[blockIdx.x] = sh[0] + sh[1] + sh[2] + sh[3];
}

__global__ void scanpartial_kernel(const int* __restrict__ partial, int* __restrict__ poffs,
                                   int* __restrict__ rowptr, int nb) {
  __shared__ int buf[256];
  int t = threadIdx.x;
  int v = (t < nb) ? partial[t] : 0;
  buf[t] = v;
  __syncthreads();
  for (int off = 1; off < 256; off <<= 1) {
    int add = (t >= off) ? buf[t - off] : 0;
    __syncthreads();
    buf[t] += add;
    __syncthreads();
  }
  if (t < nb) poffs[t] = buf[t] - v;   // exclusive
  if (t == 0) rowptr[NN] = EE;
}

__global__ void scatter_scan_kernel(const int* __restrict__ cnti, const int* __restrict__ poffs,
                                    int* __restrict__ rowptr, int* __restrict__ wtr, int n) {
  __shared__ int buf[256];
  int t = threadIdx.x;
  int i = blockIdx.x * 256 + t;
  int v = (i < n) ? cnti[i] : 0;
  buf[t] = v;
  __syncthreads();
  for (int off = 1; off < 256; off <<= 1) {
    int add = (t >= off) ? buf[t - off] : 0;
    __syncthreads();
    buf[t] += add;
    __syncthreads();
  }
  if (i < n) {
    int r = poffs[blockIdx.x] + buf[t] - v;
    rowptr[i] = r;
    wtr[i] = r;
  }
}

// pack (src<<5)|attr into one int per edge
__global__ void place_kernel(const int* __restrict__ src, const int* __restrict__ dst,
                             const int* __restrict__ attr, int* __restrict__ wtr,
                             int* __restrict__ cpack, int E) {
  int e = blockIdx.x * blockDim.x + threadIdx.x;
  if (e >= E) return;
  int p = atomicAdd(&wtr[dst[e]], 1);
  cpack[p] = (src[e] << 5) | attr[e];
}

// ---------------- fused GAT aggregate: ONE WAVE PER DST NODE, single pass ---
// out = (sum_j ex_j*v_j + exl*v_node) / den  — normalization folded out of the
// loop, so pass1/pass2 merge: every lane redundantly computes the scalar ex
// (cpack/ssrc reads are wave-broadcast; ~deg expf per lane, VALU was idle)
// and accumulates its own 2 columns. No LDS, no shuffles, no CAP limit.
// Dependent cpack->hp address chain broken by group-of-4 cpack reg prefetch.
__global__ __launch_bounds__(256) void gat_gather_kernel(
    const int* __restrict__ rowptr, const int* __restrict__ cpack,
    const float* __restrict__ table,
    const float* __restrict__ ssrc, const float* __restrict__ sdst,
    const unsigned short* __restrict__ hp, const float* __restrict__ bias,
    unsigned short* __restrict__ hout, int n) {
  const int lane = threadIdx.x & 63;
  const int node = (blockIdx.x * blockDim.x + threadIdx.x) >> 6;
  if (node >= n) return;
  const int j0 = rowptr[node], j1 = rowptr[node + 1];
  const int deg = j1 - j0;
  const float sd = sdst[node];
  const int c = lane * 2;
  float den = 0.f, esum = 0.f;
  float2 acc = make_float2(0.f, 0.f);

  int pkc[4], pkn[4];
  {
    int m0 = deg < 4 ? deg : 4;
#pragma unroll
    for (int q = 0; q < 4; q++) pkc[q] = (q < m0) ? cpack[j0 + q] : 0;
  }
  for (int j = j0; j < j1; j += 4) {
    const int m = (j1 - j) < 4 ? (j1 - j) : 4;
    const int nn2 = (j1 - j - 4) < 4 ? (j1 - j - 4) : 4;   // next group size
#pragma unroll
    for (int q = 0; q < 4; q++) pkn[q] = (q < nn2) ? cpack[j + 4 + q] : 0;
#pragma unroll
    for (int q = 0; q < 4; q++) {
      if (q < m) {
        int pk_ = pkc[q];
        int s = pk_ >> 5;
        float t = table[pk_ & 31];
        float l = ssrc[s] + sd + t;
        l = (l > 0.f) ? l : NEG_SLOPE * l;
        float ex = expf(l);
        unsigned w = *(const unsigned*)&hp[(size_t)s * DD + c];
        den += ex; esum += t;
        acc.x += ex * bflo(w); acc.y += ex * bfhi(w);
      }
    }
#pragma unroll
    for (int q = 0; q < 4; q++) pkc[q] = pkn[q];
  }

  // self-loop (edge vector = mean of incoming -> table-space mean)
  float tl = esum / fmaxf((float)deg, 1.f);
  float ll = ssrc[node] + sd + tl;
  ll = (ll > 0.f) ? ll : NEG_SLOPE * ll;
  float exl = expf(ll);
  den += exl;
  {
    unsigned w = *(const unsigned*)&hp[(size_t)node * DD + c];
    acc.x += exl * bflo(w); acc.y += exl * bfhi(w);
  }
  const float inv = 1.f / (den + 1e-16f);
  acc.x = fmaxf(acc.x * inv + bias[c], 0.f);
  acc.y = fmaxf(acc.y * inv + bias[c + 1], 0.f);
  unsigned o = (unsigned)f2bf(acc.x) | ((unsigned)f2bf(acc.y) << 16);
  *(unsigned*)&hout[(size_t)node * DD + c] = o;
}

__global__ void pool_kernel(const unsigned short* __restrict__ h, float* __restrict__ g, int n) {
  __shared__ float sh[128];
  int tid = threadIdx.x;
  int cp = tid & 63, half = tid >> 6;     // 4 row-groups, lane owns 2 cols
  float sx = 0.f, sy = 0.f;
  for (int r = blockIdx.x * 4 + half; r < n; r += gridDim.x * 4) {
    unsigned w = *(const unsigned*)&h[(size_t)r * DD + cp * 2];
    sx += bflo(w); sy += bfhi(w);
  }
  if (half == 0) { sh[cp * 2] = sx; sh[cp * 2 + 1] = sy; }
  __syncthreads();
  if (half == 1) { sh[cp * 2] += sx; sh[cp * 2 + 1] += sy; }
  __syncthreads();
  if (half == 2) { sh[cp * 2] += sx; sh[cp * 2 + 1] += sy; }
  __syncthreads();
  if (half == 3) {
    atomicAdd(&g[cp * 2], sh[cp * 2] + sx);
    atomicAdd(&g[cp * 2 + 1], sh[cp * 2 + 1] + sy);
  }
}

__global__ void readout_kernel(const float* __restrict__ g, const float* __restrict__ Wr1,
                               const float* __restrict__ br1, const float* __restrict__ Wr2,
                               const float* __restrict__ br2, float* __restrict__ out,
                               float inv_n) {
  __shared__ float gl[128];
  __shared__ float m[64];
  int t = threadIdx.x;  // 64 threads
  gl[t] = g[t] * inv_n;
  gl[t + 64] = g[t + 64] * inv_n;
  __syncthreads();
  {
    float acc = br1[t];
    for (int c = 0; c < 128; c++) acc += gl[c] * Wr1[c * 64 + t];
    m[t] = fmaxf(acc, 0.f);
  }
  __syncthreads();
  if (t < 32) {
    float acc = br2[t];
    for (int j = 0; j < 64; j++) acc += m[j] * Wr2[j * 32 + t];
    out[t] = acc;
  }
}

// ---------------- launch ----------------
extern "C" void kernel_launch(void* const* d_in, const int* in_sizes, int n_in,
                              void* d_out, int out_size, void* d_ws, size_t ws_size,
                              hipStream_t stream) {
  const float* x     = (const float*)d_in[0];
  const int*   ei    = (const int*)d_in[1];
  const int*   eattr = (const int*)d_in[2];
  const float* W1 = (const float*)d_in[3];
  const float* b1 = (const float*)d_in[4];
  const float* W2 = (const float*)d_in[5];
  const float* b2 = (const float*)d_in[6];
  const float* rel_emb = (const float*)d_in[7];
  const float* lin[2]      = {(const float*)d_in[8],  (const float*)d_in[14]};
  const float* att_src[2]  = {(const float*)d_in[9],  (const float*)d_in[15]};
  const float* att_dst[2]  = {(const float*)d_in[10], (const float*)d_in[16]};
  const float* att_edge[2] = {(const float*)d_in[11], (const float*)d_in[17]};
  const float* line[2]     = {(const float*)d_in[12], (const float*)d_in[18]};
  const float* bias[2]     = {(const float*)d_in[13], (const float*)d_in[19]};
  const float* Wr1 = (const float*)d_in[20];
  const float* br1 = (const float*)d_in[21];
  const float* Wr2 = (const float*)d_in[22];
  const float* br2 = (const float*)d_in[23];
  float* out = (float*)d_out;

  const int* srcv = ei;
  const int* dstv = ei + EE;

  char* wsb = (char*)d_ws;
  unsigned short* hA  = (unsigned short*)(wsb + 0);
  unsigned short* hp  = (unsigned short*)(wsb + 12900000);
  unsigned short* hB  = (unsigned short*)(wsb + 25900000);
  unsigned short* mid = (unsigned short*)(wsb + 38800000);
  unsigned short* W1T   = (unsigned short*)(wsb + 64600000);
  unsigned short* W2L1T = (unsigned short*)(wsb + 64900000);   // [128][256] bf16
  unsigned short* lin2T = (unsigned short*)(wsb + 65040000);
  int* rowptr  = (int*)(wsb + 65100000);
  int* wtr     = (int*)(wsb + 65300008);
  int* cnti    = (int*)(wsb + 65500008);
  int* cpack   = (int*)(wsb + 65700008);
  float* ssrc  = (float*)(wsb + 68100008);
  float* sdst  = (float*)(wsb + 68300008);
  int* partial = (int*)(wsb + 68500008);
  int* poffs   = (int*)(wsb + 68501032);
  float* tables = (float*)(wsb + 68502056);   // [2][32]
  float* g      = (float*)(wsb + 68502312);   // 128 f32
  float* b2l1   = (float*)(wsb + 68502824);   // 128 f32

  dim3 blk(256);
  const int NBLK = (NN + 255) / 256;  // 196

  hipMemsetAsync(cnti, 0, NN * sizeof(int), stream);
  hipMemsetAsync(g, 0, 128 * sizeof(float), stream);

  // weight prep (W1T, l2T, tables, W2L1 = W2@lin1, b2l1 = b2@lin1)
  prep_kernel<<<dim3(770), blk, 0, stream>>>(
      W1, W2, lin[0], lin[1], line[0], line[1], att_edge[0], att_edge[1],
      rel_emb, b2, W1T, W2L1T, lin2T, tables, b2l1);
  gemm1_fused<<<dim3(782, 2), blk, 0, stream>>>(x, W1T, b1, mid);

  // CSR build (once; both layers reuse)
  cnti_kernel<<<dim3((EE + 255) / 256), blk, 0, stream>>>(dstv, cnti, EE);
  partial_kernel<<<dim3(NBLK), blk, 0, stream>>>(cnti, partial, NN);
  scanpartial_kernel<<<1, 256, 0, stream>>>(partial, poffs, rowptr, NBLK);
  scatter_scan_kernel<<<dim3(NBLK), blk, 0, stream>>>(cnti, poffs, rowptr, wtr, NN);
  place_kernel<<<dim3((EE + 255) / 256), blk, 0, stream>>>(srcv, dstv, eattr, wtr, cpack, EE);

  // layer 1: hp = mid @ W2L1 + b2l1 (gemm2+lin1 fused) + DOTS -> gather -> hB
  gemm_mfma<true, false, true, true><<<dim3(391, 1), blk, 0, stream>>>(
      mid, W2L1T, b2l1, hp, NN, 128, 256, att_src[0], att_dst[0], ssrc, sdst);
  gat_gather_kernel<<<dim3((NN * 64 + 255) / 256), blk, 0, stream>>>(
      rowptr, cpack, tables, ssrc, sdst, hp, bias[0], hB, NN);
  // layer 2: hB -> (lin2+DOTS) hp,ssrc,sdst -> (gather) hA
  gemm_mfma<true, false, false, true><<<dim3(391, 1), blk, 0, stream>>>(
      hB, lin2T, nullptr, hp, NN, 128, 128, att_src[1], att_dst[1], ssrc, sdst);
  gat_gather_kernel<<<dim3((NN * 64 + 255) / 256), blk, 0, stream>>>(
      rowptr, cpack, tables + 32, ssrc, sdst, hp, bias[1], hA, NN);

  pool_kernel<<<dim3(256), blk, 0, stream>>>(hA, g, NN);
  readout_kernel<<<1, 64, 0, stream>>>(g, Wr1, br1, Wr2, br2, out, 1.0f / NN);
}

// Round 20
// 288.234 us; speedup vs baseline: 1.1716x; 1.1716x over previous
//
#include <hip/hip_runtime.h>
#include <hip/hip_bf16.h>

#define NN   50000
#define EE   600000
#define DINK 518
#define KP1  576          // padded K for encoder GEMM1 (9*64)
#define MP   50048        // padded rows (391*128)
#define DD   128
#define NEG_SLOPE 0.2f
#define CAP  256          // per-wave LDS stash (max in-degree fast path)

typedef short bf16x8 __attribute__((ext_vector_type(8)));
typedef float f32x4 __attribute__((ext_vector_type(4)));

typedef const __attribute__((address_space(1))) void* gp1_t;
typedef __attribute__((address_space(3))) void* lp3_t;

__device__ __forceinline__ void load_lds16(const void* g, void* l) {
  __builtin_amdgcn_global_load_lds((gp1_t)g, (lp3_t)l, 16, 0, 0);
}

__device__ __forceinline__ unsigned short f2bf(float f) {
  union { float f; unsigned u; } q; q.f = f;
  unsigned u = q.u + 0x7FFFu + ((q.u >> 16) & 1u);   // RNE
  return (unsigned short)(u >> 16);
}
__device__ __forceinline__ float bflo(unsigned u) {
  union { unsigned u; float f; } q; q.u = u << 16; return q.f;
}
__device__ __forceinline__ float bfhi(unsigned u) {
  union { unsigned u; float f; } q; q.u = u & 0xFFFF0000u; return q.f;
}

// ---------------- bf16 MFMA GEMM:  C = act(A @ BT^T [+ bias]) ----------------
// A:[Mpad][K] bf16 row-major; BT:[Ncols][K] bf16. 128x128 tile, BK=64, 4 waves.
// DOTS (bn==0, Ncols==128): also emit ssrc/sdst = (C row).att_{src,dst}
// from the fp32 accumulators (+bias when HASBIAS) — replaces sdots kernel.
template<bool OUT_BF16, bool RELU, bool HASBIAS, bool DOTS>
__global__ __launch_bounds__(256) void gemm_mfma(
    const unsigned short* __restrict__ A, const unsigned short* __restrict__ BT,
    const float* __restrict__ bias, void* __restrict__ Cout,
    int M, int Ncols, int K,
    const float* __restrict__ att_src, const float* __restrict__ att_dst,
    float* __restrict__ ssrc, float* __restrict__ sdst) {
  __shared__ short As[128][64];
  __shared__ short Bs[128][64];
  __shared__ float sp[128], dp[128];
  const int tid = threadIdx.x;
  const int lane = tid & 63;
  const int wid = tid >> 6;
  const int wr = wid >> 1, wc = wid & 1;
  const int bm = blockIdx.x * 128;
  const int bn = blockIdx.y * 128;
  const int ar = tid >> 3;
  const int ac = (tid & 7) * 8;

  f32x4 acc[4][4] = {};

  for (int k0 = 0; k0 < K; k0 += 64) {
#pragma unroll
    for (int i = 0; i < 4; i++)
      load_lds16(A + (size_t)(bm + ar + i * 32) * K + k0 + ac, &As[ar + i * 32][ac]);
#pragma unroll
    for (int i = 0; i < 4; i++)
      load_lds16(BT + (size_t)(bn + ar + i * 32) * K + k0 + ac, &Bs[ar + i * 32][ac]);
    __syncthreads();
#pragma unroll
    for (int ks = 0; ks < 2; ks++) {
      bf16x8 af[4], bfm[4];
#pragma unroll
      for (int f = 0; f < 4; f++)
        af[f] = *(const bf16x8*)&As[wr * 64 + f * 16 + (lane & 15)][ks * 32 + (lane >> 4) * 8];
#pragma unroll
      for (int f = 0; f < 4; f++)
        bfm[f] = *(const bf16x8*)&Bs[wc * 64 + f * 16 + (lane & 15)][ks * 32 + (lane >> 4) * 8];
#pragma unroll
      for (int i = 0; i < 4; i++)
#pragma unroll
        for (int j = 0; j < 4; j++)
          acc[i][j] = __builtin_amdgcn_mfma_f32_16x16x32_bf16(af[i], bfm[j], acc[i][j], 0, 0, 0);
    }
    __syncthreads();
  }

  // C/D layout (m89/m91): col = lane&15, row = (lane>>4)*4 + reg
  const int col0 = bn + wc * 64 + (lane & 15);
  const int row0 = bm + wr * 64 + (lane >> 4) * 4;
#pragma unroll
  for (int i = 0; i < 4; i++) {
#pragma unroll
    for (int jf = 0; jf < 4; jf++) {
      int col = col0 + jf * 16;
      float bv = HASBIAS ? bias[col] : 0.f;
#pragma unroll
      for (int j = 0; j < 4; j++) {
        int row = row0 + i * 16 + j;
        if (row < M) {
          float v = acc[i][jf][j] + bv;
          if (RELU) v = fmaxf(v, 0.f);
          if (OUT_BF16)
            ((unsigned short*)Cout)[(size_t)row * Ncols + col] = f2bf(v);
          else
            ((float*)Cout)[(size_t)row * Ncols + col] = v;
        }
      }
    }
  }

  if (DOTS) {
    float as_[4], ad_[4], bv_[4];
#pragma unroll
    for (int jf = 0; jf < 4; jf++) {
      int col = col0 + jf * 16;           // bn==0, covers 0..127 across wc
      as_[jf] = att_src[col];
      ad_[jf] = att_dst[col];
      bv_[jf] = HASBIAS ? bias[col] : 0.f;
    }
    float ps[4][4], pd[4][4];
#pragma unroll
    for (int i = 0; i < 4; i++) {
#pragma unroll
      for (int j = 0; j < 4; j++) {
        float s = 0.f, d = 0.f;
#pragma unroll
        for (int jf = 0; jf < 4; jf++) {
          float vv = acc[i][jf][j] + bv_[jf];
          s += vv * as_[jf];
          d += vv * ad_[jf];
        }
#pragma unroll
        for (int off = 1; off < 16; off <<= 1) {   // butterfly over lane&15 (cols)
          s += __shfl_xor(s, off);
          d += __shfl_xor(d, off);
        }
        ps[i][j] = s; pd[i][j] = d;
      }
    }
    // cross-wave (wc) combine via LDS; local row = wr*64 + i*16 + (lane>>4)*4 + j
    if (wc == 0 && (lane & 15) == 0) {
#pragma unroll
      for (int i = 0; i < 4; i++)
#pragma unroll
        for (int j = 0; j < 4; j++) {
          int r = wr * 64 + i * 16 + (lane >> 4) * 4 + j;
          sp[r] = ps[i][j]; dp[r] = pd[i][j];
        }
    }
    __syncthreads();
    if (wc == 1 && (lane & 15) == 0) {
#pragma unroll
      for (int i = 0; i < 4; i++)
#pragma unroll
        for (int j = 0; j < 4; j++) {
          int r = wr * 64 + i * 16 + (lane >> 4) * 4 + j;
          sp[r] += ps[i][j]; dp[r] += pd[i][j];
        }
    }
    __syncthreads();
    if (tid < 128) {
      int gr = bm + tid;
      if (gr < M) { ssrc[gr] = sp[tid]; sdst[gr] = dp[tid]; }
    }
  }
}

// ---------------- GEMM1 with fused fp32->bf16 A conversion ----------------
// Round-13 proven config (72us, 35% occ): BM=64/BN=128, two-phase staging.
__global__ __launch_bounds__(256) void gemm1_fused(
    const float* __restrict__ x, const unsigned short* __restrict__ BT,
    const float* __restrict__ bias, unsigned short* __restrict__ Cout) {
  __shared__ short As[64][64];
  __shared__ short Bs[128][64];
  const int tid = threadIdx.x;
  const int lane = tid & 63;
  const int wid = tid >> 6;             // wave id = column-tile owner
  const int bm = blockIdx.x * 64;
  const int bn = blockIdx.y * 128;
  const int br = tid >> 3;              // B loader row 0..31
  const int bc = (tid & 7) * 8;
  const int rlane = lane >> 5;          // 0/1: which of the 2 rows per instr
  const int klane = (lane & 31) * 2;    // k-offset 0..62

  f32x4 acc[4][2] = {};

  for (int k0 = 0; k0 < KP1; k0 += 64) {
#pragma unroll
    for (int i = 0; i < 4; i++)
      load_lds16(BT + (size_t)(bn + br + i * 32) * KP1 + k0 + bc, &Bs[br + i * 32][bc]);
    // phase 1: issue all A loads (statically indexed -> registers)
    float2 v[8];
    const int kk = k0 + klane;
    const bool kok = (kk < DINK);
#pragma unroll
    for (int i = 0; i < 8; i++) {
      int grow = bm + wid * 16 + i * 2 + rlane;
      v[i] = make_float2(0.f, 0.f);
      if (kok && grow < NN) v[i] = *(const float2*)&x[(size_t)grow * DINK + kk];
    }
    // phase 2: convert + LDS write
#pragma unroll
    for (int i = 0; i < 8; i++) {
      int rl = wid * 16 + i * 2 + rlane;
      unsigned pk;
      asm("v_cvt_pk_bf16_f32 %0, %1, %2" : "=v"(pk) : "v"(v[i].x), "v"(v[i].y));
      *(unsigned*)&As[rl][klane] = pk;
    }
    __syncthreads();
#pragma unroll
    for (int ks = 0; ks < 2; ks++) {
      bf16x8 af[4], bfm[2];
#pragma unroll
      for (int f = 0; f < 4; f++)
        af[f] = *(const bf16x8*)&As[f * 16 + (lane & 15)][ks * 32 + (lane >> 4) * 8];
#pragma unroll
      for (int f = 0; f < 2; f++)
        bfm[f] = *(const bf16x8*)&Bs[wid * 32 + f * 16 + (lane & 15)][ks * 32 + (lane >> 4) * 8];
#pragma unroll
      for (int i = 0; i < 4; i++)
#pragma unroll
        for (int j = 0; j < 2; j++)
          acc[i][j] = __builtin_amdgcn_mfma_f32_16x16x32_bf16(af[i], bfm[j], acc[i][j], 0, 0, 0);
    }
    __syncthreads();
  }

  const int col0 = bn + wid * 32 + (lane & 15);
  const int row0 = bm + (lane >> 4) * 4;
#pragma unroll
  for (int i = 0; i < 4; i++) {
#pragma unroll
    for (int jf = 0; jf < 2; jf++) {
      int col = col0 + jf * 16;
      float bv = bias[col];
#pragma unroll
      for (int j = 0; j < 4; j++) {
        int row = row0 + i * 16 + j;
        if (row < NN) {
          float v2 = fmaxf(acc[i][jf][j] + bv, 0.f);
          Cout[(size_t)row * 256 + col] = f2bf(v2);
        }
      }
    }
  }
}

// -------- combined weight prep: W1T, l2T, tables, and W2L1 = W2@lin1 --------
__device__ __forceinline__ void convT_body(const float* __restrict__ W,
                                           unsigned short* __restrict__ WT,
                                           int K, int Ncols, int Kpad, int t) {
  int n = t / Kpad, k = t % Kpad;
  float v = (k < K) ? W[(size_t)k * Ncols + n] : 0.f;
  WT[(size_t)n * Kpad + k] = f2bf(v);
}

__global__ __launch_bounds__(256) void prep_kernel(
    const float* __restrict__ W1, const float* __restrict__ W2,
    const float* __restrict__ l1, const float* __restrict__ l2,
    const float* __restrict__ le1, const float* __restrict__ le2,
    const float* __restrict__ ae1, const float* __restrict__ ae2,
    const float* __restrict__ rel_emb, const float* __restrict__ b2,
    unsigned short* __restrict__ W1T, unsigned short* __restrict__ W2L1T,
    unsigned short* __restrict__ l2T, float* __restrict__ tables,
    float* __restrict__ b2l1) {
  const int b = blockIdx.x, tid = threadIdx.x;
  if (b < 576) { convT_body(W1, W1T, DINK, 256, KP1, b * 256 + tid); return; }
  if (b < 640) { convT_body(l2, l2T, 128, 128, 128, (b - 576) * 256 + tid); return; }
  if (b < 642) {
    // tables[layer][r] = rel_emb[r] . (line @ att_edge)
    const int layer = b - 640;
    const float* line = layer ? le2 : le1;
    const float* ae   = layer ? ae2 : ae1;
    __shared__ float ve[32];
    if (tid < 32) {
      float s = 0.f;
      for (int d = 0; d < 128; d++) s += line[tid * 128 + d] * ae[d];
      ve[tid] = s;
    }
    __syncthreads();
    if (tid < 26) {
      float s = 0.f;
      for (int j = 0; j < 32; j++) s += rel_emb[tid * 32 + j] * ve[j];
      tables[layer * 32 + tid] = s;
    }
    return;
  }
  // W2L1T[n][k] = sum_j W2[k][j]*lin1[j][n]  (n = output col, k = 0..255)
  const int n = b - 642;
  __shared__ float lc[128];
  if (tid < 128) lc[tid] = l1[(size_t)tid * 128 + n];
  __syncthreads();
  float s = 0.f;
  const float* wrow = W2 + (size_t)tid * 128;
  for (int j = 0; j < 128; j++) s += wrow[j] * lc[j];
  W2L1T[(size_t)n * 256 + tid] = f2bf(s);
  if (tid == 0) {
    float bb = 0.f;
    for (int j = 0; j < 128; j++) bb += b2[j] * lc[j];
    b2l1[n] = bb;
  }
}

// ---------------- CSR build (counting sort by dst; reused by both layers) ----
__global__ void cnti_kernel(const int* __restrict__ dst, int* __restrict__ cnti, int E) {
  int e = blockIdx.x * blockDim.x + threadIdx.x;
  if (e < E) atomicAdd(&cnti[dst[e]], 1);
}

__global__ void partial_kernel(const int* __restrict__ cnti, int* __restrict__ partial, int n) {
  __shared__ int sh[4];
  int i = blockIdx.x * 256 + threadIdx.x;
  int lane = threadIdx.x & 63, wid = threadIdx.x >> 6;
  int v = (i < n) ? cnti[i] : 0;
#pragma unroll
  for (int off = 32; off; off >>= 1) v += __shfl_xor(v, off);
  if (lane == 0) sh[wid] = v;
  __syncthreads();
  if (threadIdx.x == 0) partial[blockIdx.x] = sh[0] + sh[1] + sh[2] + sh[3];
}

__global__ void scanpartial_kernel(const int* __restrict__ partial, int* __restrict__ poffs,
                                   int* __restrict__ rowptr, int nb) {
  __shared__ int buf[256];
  int t = threadIdx.x;
  int v = (t < nb) ? partial[t] : 0;
  buf[t] = v;
  __syncthreads();
  for (int off = 1; off < 256; off <<= 1) {
    int add = (t >= off) ? buf[t - off] : 0;
    __syncthreads();
    buf[t] += add;
    __syncthreads();
  }
  if (t < nb) poffs[t] = buf[t] - v;   // exclusive
  if (t == 0) rowptr[NN] = EE;
}

__global__ void scatter_scan_kernel(const int* __restrict__ cnti, const int* __restrict__ poffs,
                                    int* __restrict__ rowptr, int* __restrict__ wtr, int n) {
  __shared__ int buf[256];
  int t = threadIdx.x;
  int i = blockIdx.x * 256 + t;
  int v = (i < n) ? cnti[i] : 0;
  buf[t] = v;
  __syncthreads();
  for (int off = 1; off < 256; off <<= 1) {
    int add = (t >= off) ? buf[t - off] : 0;
    __syncthreads();
    buf[t] += add;
    __syncthreads();
  }
  if (i < n) {
    int r = poffs[blockIdx.x] + buf[t] - v;
    rowptr[i] = r;
    wtr[i] = r;
  }
}

// pack (src<<5)|attr into one int per edge
__global__ void place_kernel(const int* __restrict__ src, const int* __restrict__ dst,
                             const int* __restrict__ attr, int* __restrict__ wtr,
                             int* __restrict__ cpack, int E) {
  int e = blockIdx.x * blockDim.x + threadIdx.x;
  if (e >= E) return;
  int p = atomicAdd(&wtr[dst[e]], 1);
  cpack[p] = (src[e] << 5) | attr[e];
}

// ---------------- fused GAT aggregate: ONE WAVE PER DST NODE ----------------
// (two-pass form: lane-PARALLEL logits + LDS-stashed exp/addr is what hides
// the scattered ssrc/hp load latency — round-19's single-pass serialization
// of those loads regressed 25us/layer)
__global__ __launch_bounds__(256) void gat_gather_kernel(
    const int* __restrict__ rowptr, const int* __restrict__ cpack,
    const float* __restrict__ table,
    const float* __restrict__ ssrc, const float* __restrict__ sdst,
    const unsigned short* __restrict__ hp, const float* __restrict__ bias,
    unsigned short* __restrict__ hout, int n) {
  __shared__ float exs[4][CAP];
  __shared__ int   srcs[4][CAP];
  const int wid = threadIdx.x >> 6, lane = threadIdx.x & 63;
  const int node = (blockIdx.x * blockDim.x + threadIdx.x) >> 6;
  if (node >= n) return;
  const int j0 = rowptr[node], j1 = rowptr[node + 1];
  const int deg = j1 - j0;
  const float sd = sdst[node];
  float den = 0.f, esum = 0.f;
  for (int j = j0 + lane; j < j1; j += 64) {
    int pk_ = cpack[j];
    int s = pk_ >> 5;
    float t = table[pk_ & 31];
    float l = ssrc[s] + sd + t;
    l = (l > 0.f) ? l : NEG_SLOPE * l;
    float ex = expf(l);
    int k = j - j0;
    if (k < CAP) { exs[wid][k] = ex; srcs[wid][k] = s * DD; }
    den += ex; esum += t;
  }
#pragma unroll
  for (int off = 32; off; off >>= 1) {
    den += __shfl_xor(den, off);
    esum += __shfl_xor(esum, off);
  }
  // self-loop (edge vector = mean of incoming -> table-space mean)
  float tl = esum / fmaxf((float)deg, 1.f);
  float ll = ssrc[node] + sd + tl;
  ll = (ll > 0.f) ? ll : NEG_SLOPE * ll;
  float exl = expf(ll);
  den += exl;
  const float inv = 1.f / (den + 1e-16f);
  // pass 2: lane owns cols c, c+1 (one dword of bf16 per row)
  const int c = lane * 2;
  float2 acc;
  {
    unsigned w = *(const unsigned*)&hp[(size_t)node * DD + c];
    float a = exl * inv;
    acc.x = a * bflo(w); acc.y = a * bfhi(w);
  }
  const int m = deg < CAP ? deg : CAP;
  int k = 0;
  for (; k + 8 <= m; k += 8) {
    unsigned w[8]; float a[8];
#pragma unroll
    for (int q = 0; q < 8; q++) {
      a[q] = exs[wid][k + q] * inv;
      w[q] = *(const unsigned*)&hp[(size_t)(srcs[wid][k + q] + c)];
    }
#pragma unroll
    for (int q = 0; q < 8; q++) {
      acc.x += a[q] * bflo(w[q]); acc.y += a[q] * bfhi(w[q]);
    }
  }
  for (; k + 4 <= m; k += 4) {
    unsigned w[4]; float a[4];
#pragma unroll
    for (int q = 0; q < 4; q++) {
      a[q] = exs[wid][k + q] * inv;
      w[q] = *(const unsigned*)&hp[(size_t)(srcs[wid][k + q] + c)];
    }
#pragma unroll
    for (int q = 0; q < 4; q++) {
      acc.x += a[q] * bflo(w[q]); acc.y += a[q] * bfhi(w[q]);
    }
  }
  for (; k < m; k++) {
    float a0 = exs[wid][k] * inv;
    unsigned w0 = *(const unsigned*)&hp[(size_t)(srcs[wid][k] + c)];
    acc.x += a0 * bflo(w0); acc.y += a0 * bfhi(w0);
  }
  for (int j = j0 + CAP; j < j1; j++) {  // cold fallback, deg > CAP
    int pk_ = cpack[j];
    int s = pk_ >> 5;
    float t = table[pk_ & 31];
    float l = ssrc[s] + sd + t;
    l = (l > 0.f) ? l : NEG_SLOPE * l;
    float a0 = expf(l) * inv;
    unsigned w0 = *(const unsigned*)&hp[(size_t)s * DD + c];
    acc.x += a0 * bflo(w0); acc.y += a0 * bfhi(w0);
  }
  acc.x = fmaxf(acc.x + bias[c], 0.f);
  acc.y = fmaxf(acc.y + bias[c + 1], 0.f);
  unsigned o = (unsigned)f2bf(acc.x) | ((unsigned)f2bf(acc.y) << 16);
  *(unsigned*)&hout[(size_t)node * DD + c] = o;
}

__global__ void pool_kernel(const unsigned short* __restrict__ h, float* __restrict__ g, int n) {
  __shared__ float sh[128];
  int tid = threadIdx.x;
  int cp = tid & 63, half = tid >> 6;     // 4 row-groups, lane owns 2 cols
  float sx = 0.f, sy = 0.f;
  for (int r = blockIdx.x * 4 + half; r < n; r += gridDim.x * 4) {
    unsigned w = *(const unsigned*)&h[(size_t)r * DD + cp * 2];
    sx += bflo(w); sy += bfhi(w);
  }
  if (half == 0) { sh[cp * 2] = sx; sh[cp * 2 + 1] = sy; }
  __syncthreads();
  if (half == 1) { sh[cp * 2] += sx; sh[cp * 2 + 1] += sy; }
  __syncthreads();
  if (half == 2) { sh[cp * 2] += sx; sh[cp * 2 + 1] += sy; }
  __syncthreads();
  if (half == 3) {
    atomicAdd(&g[cp * 2], sh[cp * 2] + sx);
    atomicAdd(&g[cp * 2 + 1], sh[cp * 2 + 1] + sy);
  }
}

__global__ void readout_kernel(const float* __restrict__ g, const float* __restrict__ Wr1,
                               const float* __restrict__ br1, const float* __restrict__ Wr2,
                               const float* __restrict__ br2, float* __restrict__ out,
                               float inv_n) {
  __shared__ float gl[128];
  __shared__ float m[64];
  int t = threadIdx.x;  // 64 threads
  gl[t] = g[t] * inv_n;
  gl[t + 64] = g[t + 64] * inv_n;
  __syncthreads();
  {
    float acc = br1[t];
    for (int c = 0; c < 128; c++) acc += gl[c] * Wr1[c * 64 + t];
    m[t] = fmaxf(acc, 0.f);
  }
  __syncthreads();
  if (t < 32) {
    float acc = br2[t];
    for (int j = 0; j < 64; j++) acc += m[j] * Wr2[j * 32 + t];
    out[t] = acc;
  }
}

// ---------------- launch ----------------
extern "C" void kernel_launch(void* const* d_in, const int* in_sizes, int n_in,
                              void* d_out, int out_size, void* d_ws, size_t ws_size,
                              hipStream_t stream) {
  const float* x     = (const float*)d_in[0];
  const int*   ei    = (const int*)d_in[1];
  const int*   eattr = (const int*)d_in[2];
  const float* W1 = (const float*)d_in[3];
  const float* b1 = (const float*)d_in[4];
  const float* W2 = (const float*)d_in[5];
  const float* b2 = (const float*)d_in[6];
  const float* rel_emb = (const float*)d_in[7];
  const float* lin[2]      = {(const float*)d_in[8],  (const float*)d_in[14]};
  const float* att_src[2]  = {(const float*)d_in[9],  (const float*)d_in[15]};
  const float* att_dst[2]  = {(const float*)d_in[10], (const float*)d_in[16]};
  const float* att_edge[2] = {(const float*)d_in[11], (const float*)d_in[17]};
  const float* line[2]     = {(const float*)d_in[12], (const float*)d_in[18]};
  const float* bias[2]     = {(const float*)d_in[13], (const float*)d_in[19]};
  const float* Wr1 = (const float*)d_in[20];
  const float* br1 = (const float*)d_in[21];
  const float* Wr2 = (const float*)d_in[22];
  const float* br2 = (const float*)d_in[23];
  float* out = (float*)d_out;

  const int* srcv = ei;
  const int* dstv = ei + EE;

  char* wsb = (char*)d_ws;
  unsigned short* hA  = (unsigned short*)(wsb + 0);
  unsigned short* hp  = (unsigned short*)(wsb + 12900000);
  unsigned short* hB  = (unsigned short*)(wsb + 25900000);
  unsigned short* mid = (unsigned short*)(wsb + 38800000);
  unsigned short* W1T   = (unsigned short*)(wsb + 64600000);
  unsigned short* W2L1T = (unsigned short*)(wsb + 64900000);   // [128][256] bf16
  unsigned short* lin2T = (unsigned short*)(wsb + 65040000);
  int* rowptr  = (int*)(wsb + 65100000);
  int* wtr     = (int*)(wsb + 65300008);
  int* cnti    = (int*)(wsb + 65500008);
  int* cpack   = (int*)(wsb + 65700008);
  float* ssrc  = (float*)(wsb + 68100008);
  float* sdst  = (float*)(wsb + 68300008);
  int* partial = (int*)(wsb + 68500008);
  int* poffs   = (int*)(wsb + 68501032);
  float* tables = (float*)(wsb + 68502056);   // [2][32]
  float* g      = (float*)(wsb + 68502312);   // 128 f32
  float* b2l1   = (float*)(wsb + 68502824);   // 128 f32

  dim3 blk(256);
  const int NBLK = (NN + 255) / 256;  // 196

  hipMemsetAsync(cnti, 0, NN * sizeof(int), stream);
  hipMemsetAsync(g, 0, 128 * sizeof(float), stream);

  // weight prep (W1T, l2T, tables, W2L1 = W2@lin1, b2l1 = b2@lin1)
  prep_kernel<<<dim3(770), blk, 0, stream>>>(
      W1, W2, lin[0], lin[1], line[0], line[1], att_edge[0], att_edge[1],
      rel_emb, b2, W1T, W2L1T, lin2T, tables, b2l1);
  gemm1_fused<<<dim3(782, 2), blk, 0, stream>>>(x, W1T, b1, mid);

  // CSR build (once; both layers reuse)
  cnti_kernel<<<dim3((EE + 255) / 256), blk, 0, stream>>>(dstv, cnti, EE);
  partial_kernel<<<dim3(NBLK), blk, 0, stream>>>(cnti, partial, NN);
  scanpartial_kernel<<<1, 256, 0, stream>>>(partial, poffs, rowptr, NBLK);
  scatter_scan_kernel<<<dim3(NBLK), blk, 0, stream>>>(cnti, poffs, rowptr, wtr, NN);
  place_kernel<<<dim3((EE + 255) / 256), blk, 0, stream>>>(srcv, dstv, eattr, wtr, cpack, EE);

  // layer 1: hp = mid @ W2L1 + b2l1 (gemm2+lin1 fused) + DOTS -> gather -> hB
  gemm_mfma<true, false, true, true><<<dim3(391, 1), blk, 0, stream>>>(
      mid, W2L1T, b2l1, hp, NN, 128, 256, att_src[0], att_dst[0], ssrc, sdst);
  gat_gather_kernel<<<dim3((NN * 64 + 255) / 256), blk, 0, stream>>>(
      rowptr, cpack, tables, ssrc, sdst, hp, bias[0], hB, NN);
  // layer 2: hB -> (lin2+DOTS) hp,ssrc,sdst -> (gather) hA
  gemm_mfma<true, false, false, true><<<dim3(391, 1), blk, 0, stream>>>(
      hB, lin2T, nullptr, hp, NN, 128, 128, att_src[1], att_dst[1], ssrc, sdst);
  gat_gather_kernel<<<dim3((NN * 64 + 255) / 256), blk, 0, stream>>>(
      rowptr, cpack, tables + 32, ssrc, sdst, hp, bias[1], hA, NN);

  pool_kernel<<<dim3(256), blk, 0, stream>>>(hA, g, NN);
  readout_kernel<<<1, 64, 0, stream>>>(g, Wr1, br1, Wr2, br2, out, 1.0f / NN);
}

// Round 21
// 231.882 us; speedup vs baseline: 1.4563x; 1.2430x over previous
//
#include <hip/hip_runtime.h>
#include <hip/hip_bf16.h>

#define NN   50000
#define EE   600000
#define DINK 518
#define KP1  576          // padded K for encoder GEMM1 (9*64)
#define MP   50048        // padded rows (391*128)
#define DD   128
#define NEG_SLOPE 0.2f
#define CAP  64           // bucket capacity per node (deg ~ Poisson(12); P(>64)~1e-24)

typedef short bf16x8 __attribute__((ext_vector_type(8)));
typedef float f32x4 __attribute__((ext_vector_type(4)));

typedef const __attribute__((address_space(1))) void* gp1_t;
typedef __attribute__((address_space(3))) void* lp3_t;

__device__ __forceinline__ void load_lds16(const void* g, void* l) {
  __builtin_amdgcn_global_load_lds((gp1_t)g, (lp3_t)l, 16, 0, 0);
}

__device__ __forceinline__ unsigned short f2bf(float f) {
  union { float f; unsigned u; } q; q.f = f;
  unsigned u = q.u + 0x7FFFu + ((q.u >> 16) & 1u);   // RNE
  return (unsigned short)(u >> 16);
}
__device__ __forceinline__ float bflo(unsigned u) {
  union { unsigned u; float f; } q; q.u = u << 16; return q.f;
}
__device__ __forceinline__ float bfhi(unsigned u) {
  union { unsigned u; float f; } q; q.u = u & 0xFFFF0000u; return q.f;
}

// ---------------- bf16 MFMA GEMM:  C = act(A @ BT^T [+ bias]) ----------------
// A:[Mpad][K] bf16 row-major; BT:[Ncols][K] bf16. 128x128 tile, BK=64, 4 waves.
// DOTS (bn==0, Ncols==128): also emit ssrc/sdst = (C row).att_{src,dst}
// from the fp32 accumulators (+bias when HASBIAS) — replaces sdots kernel.
template<bool OUT_BF16, bool RELU, bool HASBIAS, bool DOTS>
__global__ __launch_bounds__(256) void gemm_mfma(
    const unsigned short* __restrict__ A, const unsigned short* __restrict__ BT,
    const float* __restrict__ bias, void* __restrict__ Cout,
    int M, int Ncols, int K,
    const float* __restrict__ att_src, const float* __restrict__ att_dst,
    float* __restrict__ ssrc, float* __restrict__ sdst) {
  __shared__ short As[128][64];
  __shared__ short Bs[128][64];
  __shared__ float sp[128], dp[128];
  const int tid = threadIdx.x;
  const int lane = tid & 63;
  const int wid = tid >> 6;
  const int wr = wid >> 1, wc = wid & 1;
  const int bm = blockIdx.x * 128;
  const int bn = blockIdx.y * 128;
  const int ar = tid >> 3;
  const int ac = (tid & 7) * 8;

  f32x4 acc[4][4] = {};

  for (int k0 = 0; k0 < K; k0 += 64) {
#pragma unroll
    for (int i = 0; i < 4; i++)
      load_lds16(A + (size_t)(bm + ar + i * 32) * K + k0 + ac, &As[ar + i * 32][ac]);
#pragma unroll
    for (int i = 0; i < 4; i++)
      load_lds16(BT + (size_t)(bn + ar + i * 32) * K + k0 + ac, &Bs[ar + i * 32][ac]);
    __syncthreads();
#pragma unroll
    for (int ks = 0; ks < 2; ks++) {
      bf16x8 af[4], bfm[4];
#pragma unroll
      for (int f = 0; f < 4; f++)
        af[f] = *(const bf16x8*)&As[wr * 64 + f * 16 + (lane & 15)][ks * 32 + (lane >> 4) * 8];
#pragma unroll
      for (int f = 0; f < 4; f++)
        bfm[f] = *(const bf16x8*)&Bs[wc * 64 + f * 16 + (lane & 15)][ks * 32 + (lane >> 4) * 8];
#pragma unroll
      for (int i = 0; i < 4; i++)
#pragma unroll
        for (int j = 0; j < 4; j++)
          acc[i][j] = __builtin_amdgcn_mfma_f32_16x16x32_bf16(af[i], bfm[j], acc[i][j], 0, 0, 0);
    }
    __syncthreads();
  }

  // C/D layout (m89/m91): col = lane&15, row = (lane>>4)*4 + reg
  const int col0 = bn + wc * 64 + (lane & 15);
  const int row0 = bm + wr * 64 + (lane >> 4) * 4;
#pragma unroll
  for (int i = 0; i < 4; i++) {
#pragma unroll
    for (int jf = 0; jf < 4; jf++) {
      int col = col0 + jf * 16;
      float bv = HASBIAS ? bias[col] : 0.f;
#pragma unroll
      for (int j = 0; j < 4; j++) {
        int row = row0 + i * 16 + j;
        if (row < M) {
          float v = acc[i][jf][j] + bv;
          if (RELU) v = fmaxf(v, 0.f);
          if (OUT_BF16)
            ((unsigned short*)Cout)[(size_t)row * Ncols + col] = f2bf(v);
          else
            ((float*)Cout)[(size_t)row * Ncols + col] = v;
        }
      }
    }
  }

  if (DOTS) {
    float as_[4], ad_[4], bv_[4];
#pragma unroll
    for (int jf = 0; jf < 4; jf++) {
      int col = col0 + jf * 16;           // bn==0, covers 0..127 across wc
      as_[jf] = att_src[col];
      ad_[jf] = att_dst[col];
      bv_[jf] = HASBIAS ? bias[col] : 0.f;
    }
    float ps[4][4], pd[4][4];
#pragma unroll
    for (int i = 0; i < 4; i++) {
#pragma unroll
      for (int j = 0; j < 4; j++) {
        float s = 0.f, d = 0.f;
#pragma unroll
        for (int jf = 0; jf < 4; jf++) {
          float vv = acc[i][jf][j] + bv_[jf];
          s += vv * as_[jf];
          d += vv * ad_[jf];
        }
#pragma unroll
        for (int off = 1; off < 16; off <<= 1) {   // butterfly over lane&15 (cols)
          s += __shfl_xor(s, off);
          d += __shfl_xor(d, off);
        }
        ps[i][j] = s; pd[i][j] = d;
      }
    }
    // cross-wave (wc) combine via LDS; local row = wr*64 + i*16 + (lane>>4)*4 + j
    if (wc == 0 && (lane & 15) == 0) {
#pragma unroll
      for (int i = 0; i < 4; i++)
#pragma unroll
        for (int j = 0; j < 4; j++) {
          int r = wr * 64 + i * 16 + (lane >> 4) * 4 + j;
          sp[r] = ps[i][j]; dp[r] = pd[i][j];
        }
    }
    __syncthreads();
    if (wc == 1 && (lane & 15) == 0) {
#pragma unroll
      for (int i = 0; i < 4; i++)
#pragma unroll
        for (int j = 0; j < 4; j++) {
          int r = wr * 64 + i * 16 + (lane >> 4) * 4 + j;
          sp[r] += ps[i][j]; dp[r] += pd[i][j];
        }
    }
    __syncthreads();
    if (tid < 128) {
      int gr = bm + tid;
      if (gr < M) { ssrc[gr] = sp[tid]; sdst[gr] = dp[tid]; }
    }
  }
}

// ---------------- GEMM1 with fused fp32->bf16 A conversion ----------------
// Round-13 proven config (72us, 35% occ): BM=64/BN=128, two-phase staging.
__global__ __launch_bounds__(256) void gemm1_fused(
    const float* __restrict__ x, const unsigned short* __restrict__ BT,
    const float* __restrict__ bias, unsigned short* __restrict__ Cout) {
  __shared__ short As[64][64];
  __shared__ short Bs[128][64];
  const int tid = threadIdx.x;
  const int lane = tid & 63;
  const int wid = tid >> 6;             // wave id = column-tile owner
  const int bm = blockIdx.x * 64;
  const int bn = blockIdx.y * 128;
  const int br = tid >> 3;              // B loader row 0..31
  const int bc = (tid & 7) * 8;
  const int rlane = lane >> 5;          // 0/1: which of the 2 rows per instr
  const int klane = (lane & 31) * 2;    // k-offset 0..62

  f32x4 acc[4][2] = {};

  for (int k0 = 0; k0 < KP1; k0 += 64) {
#pragma unroll
    for (int i = 0; i < 4; i++)
      load_lds16(BT + (size_t)(bn + br + i * 32) * KP1 + k0 + bc, &Bs[br + i * 32][bc]);
    // phase 1: issue all A loads (statically indexed -> registers)
    float2 v[8];
    const int kk = k0 + klane;
    const bool kok = (kk < DINK);
#pragma unroll
    for (int i = 0; i < 8; i++) {
      int grow = bm + wid * 16 + i * 2 + rlane;
      v[i] = make_float2(0.f, 0.f);
      if (kok && grow < NN) v[i] = *(const float2*)&x[(size_t)grow * DINK + kk];
    }
    // phase 2: convert + LDS write
#pragma unroll
    for (int i = 0; i < 8; i++) {
      int rl = wid * 16 + i * 2 + rlane;
      unsigned pk;
      asm("v_cvt_pk_bf16_f32 %0, %1, %2" : "=v"(pk) : "v"(v[i].x), "v"(v[i].y));
      *(unsigned*)&As[rl][klane] = pk;
    }
    __syncthreads();
#pragma unroll
    for (int ks = 0; ks < 2; ks++) {
      bf16x8 af[4], bfm[2];
#pragma unroll
      for (int f = 0; f < 4; f++)
        af[f] = *(const bf16x8*)&As[f * 16 + (lane & 15)][ks * 32 + (lane >> 4) * 8];
#pragma unroll
      for (int f = 0; f < 2; f++)
        bfm[f] = *(const bf16x8*)&Bs[wid * 32 + f * 16 + (lane & 15)][ks * 32 + (lane >> 4) * 8];
#pragma unroll
      for (int i = 0; i < 4; i++)
#pragma unroll
        for (int j = 0; j < 2; j++)
          acc[i][j] = __builtin_amdgcn_mfma_f32_16x16x32_bf16(af[i], bfm[j], acc[i][j], 0, 0, 0);
    }
    __syncthreads();
  }

  const int col0 = bn + wid * 32 + (lane & 15);
  const int row0 = bm + (lane >> 4) * 4;
#pragma unroll
  for (int i = 0; i < 4; i++) {
#pragma unroll
    for (int jf = 0; jf < 2; jf++) {
      int col = col0 + jf * 16;
      float bv = bias[col];
#pragma unroll
      for (int j = 0; j < 4; j++) {
        int row = row0 + i * 16 + j;
        if (row < NN) {
          float v2 = fmaxf(acc[i][jf][j] + bv, 0.f);
          Cout[(size_t)row * 256 + col] = f2bf(v2);
        }
      }
    }
  }
}

// -------- combined weight prep: W1T, l2T, tables, W2L1 = W2@lin1, and -------
// -------- zeroing of cnt (bucket counters) + g (pool accumulator) -----------
__device__ __forceinline__ void convT_body(const float* __restrict__ W,
                                           unsigned short* __restrict__ WT,
                                           int K, int Ncols, int Kpad, int t) {
  int n = t / Kpad, k = t % Kpad;
  float v = (k < K) ? W[(size_t)k * Ncols + n] : 0.f;
  WT[(size_t)n * Kpad + k] = f2bf(v);
}

__global__ __launch_bounds__(256) void prep_kernel(
    const float* __restrict__ W1, const float* __restrict__ W2,
    const float* __restrict__ l1, const float* __restrict__ l2,
    const float* __restrict__ le1, const float* __restrict__ le2,
    const float* __restrict__ ae1, const float* __restrict__ ae2,
    const float* __restrict__ rel_emb, const float* __restrict__ b2,
    unsigned short* __restrict__ W1T, unsigned short* __restrict__ W2L1T,
    unsigned short* __restrict__ l2T, float* __restrict__ tables,
    float* __restrict__ b2l1, int* __restrict__ cnt, float* __restrict__ g) {
  const int b = blockIdx.x, tid = threadIdx.x;
  if (b < 576) { convT_body(W1, W1T, DINK, 256, KP1, b * 256 + tid); return; }
  if (b < 640) { convT_body(l2, l2T, 128, 128, 128, (b - 576) * 256 + tid); return; }
  if (b < 642) {
    // tables[layer][r] = rel_emb[r] . (line @ att_edge)
    const int layer = b - 640;
    const float* line = layer ? le2 : le1;
    const float* ae   = layer ? ae2 : ae1;
    __shared__ float ve[32];
    if (tid < 32) {
      float s = 0.f;
      for (int d = 0; d < 128; d++) s += line[tid * 128 + d] * ae[d];
      ve[tid] = s;
    }
    __syncthreads();
    if (tid < 26) {
      float s = 0.f;
      for (int j = 0; j < 32; j++) s += rel_emb[tid * 32 + j] * ve[j];
      tables[layer * 32 + tid] = s;
    }
    return;
  }
  if (b < 770) {
    // W2L1T[n][k] = sum_j W2[k][j]*lin1[j][n]  (n = output col, k = 0..255)
    const int n = b - 642;
    __shared__ float lc[128];
    if (tid < 128) lc[tid] = l1[(size_t)tid * 128 + n];
    __syncthreads();
    float s = 0.f;
    const float* wrow = W2 + (size_t)tid * 128;
    for (int j = 0; j < 128; j++) s += wrow[j] * lc[j];
    W2L1T[(size_t)n * 256 + tid] = f2bf(s);
    if (tid == 0) {
      float bb = 0.f;
      for (int j = 0; j < 128; j++) bb += b2[j] * lc[j];
      b2l1[n] = bb;
    }
    return;
  }
  // b in [770, 966): zero cnt[50000]; block 770 also zeros g[128]
  {
    const int zb = b - 770;
    int i = zb * 256 + tid;
    if (i < NN) cnt[i] = 0;
    if (zb == 0 && tid < 128) g[tid] = 0.f;
  }
}

// ------- bucket build: replaces cnti+partial+scan+scatter+place (5 kernels) -
// cpack[node*CAP + p] = (src<<5)|attr; cnt[node] = in-degree.
__global__ void bucket_kernel(const int* __restrict__ src, const int* __restrict__ dst,
                              const int* __restrict__ attr, int* __restrict__ cnt,
                              int* __restrict__ cpack, int E) {
  int e = blockIdx.x * blockDim.x + threadIdx.x;
  if (e >= E) return;
  int d = dst[e];
  int p = atomicAdd(&cnt[d], 1);
  if (p < CAP) cpack[d * CAP + p] = (src[e] << 5) | attr[e];
}

// ---------------- fused GAT aggregate: ONE WAVE PER DST NODE ----------------
// two-pass form (lane-PARALLEL logits + LDS-stashed exp/addr hides scattered
// load latency). Bucketed CSR: j0 = node*CAP, deg = cnt[node] (<= CAP).
__global__ __launch_bounds__(256) void gat_gather_kernel(
    const int* __restrict__ cnt, const int* __restrict__ cpack,
    const float* __restrict__ table,
    const float* __restrict__ ssrc, const float* __restrict__ sdst,
    const unsigned short* __restrict__ hp, const float* __restrict__ bias,
    unsigned short* __restrict__ hout, int n) {
  __shared__ float exs[4][CAP];
  __shared__ int   srcs[4][CAP];
  const int wid = threadIdx.x >> 6, lane = threadIdx.x & 63;
  const int node = (blockIdx.x * blockDim.x + threadIdx.x) >> 6;
  if (node >= n) return;
  int deg = cnt[node];
  if (deg > CAP) deg = CAP;   // impossible for this graph; guards OOB
  const int j0 = node * CAP;
  const float sd = sdst[node];
  float den = 0.f, esum = 0.f;
  if (lane < deg) {           // deg <= 64: single lane-parallel step
    int pk_ = cpack[j0 + lane];
    int s = pk_ >> 5;
    float t = table[pk_ & 31];
    float l = ssrc[s] + sd + t;
    l = (l > 0.f) ? l : NEG_SLOPE * l;
    float ex = expf(l);
    exs[wid][lane] = ex; srcs[wid][lane] = s * DD;
    den = ex; esum = t;
  }
#pragma unroll
  for (int off = 32; off; off >>= 1) {
    den += __shfl_xor(den, off);
    esum += __shfl_xor(esum, off);
  }
  // self-loop (edge vector = mean of incoming -> table-space mean)
  float tl = esum / fmaxf((float)deg, 1.f);
  float ll = ssrc[node] + sd + tl;
  ll = (ll > 0.f) ? ll : NEG_SLOPE * ll;
  float exl = expf(ll);
  den += exl;
  const float inv = 1.f / (den + 1e-16f);
  // pass 2: lane owns cols c, c+1 (one dword of bf16 per row)
  const int c = lane * 2;
  float2 acc;
  {
    unsigned w = *(const unsigned*)&hp[(size_t)node * DD + c];
    float a = exl * inv;
    acc.x = a * bflo(w); acc.y = a * bfhi(w);
  }
  int k = 0;
  for (; k + 8 <= deg; k += 8) {
    unsigned w[8]; float a[8];
#pragma unroll
    for (int q = 0; q < 8; q++) {
      a[q] = exs[wid][k + q] * inv;
      w[q] = *(const unsigned*)&hp[(size_t)(srcs[wid][k + q] + c)];
    }
#pragma unroll
    for (int q = 0; q < 8; q++) {
      acc.x += a[q] * bflo(w[q]); acc.y += a[q] * bfhi(w[q]);
    }
  }
  for (; k + 4 <= deg; k += 4) {
    unsigned w[4]; float a[4];
#pragma unroll
    for (int q = 0; q < 4; q++) {
      a[q] = exs[wid][k + q] * inv;
      w[q] = *(const unsigned*)&hp[(size_t)(srcs[wid][k + q] + c)];
    }
#pragma unroll
    for (int q = 0; q < 4; q++) {
      acc.x += a[q] * bflo(w[q]); acc.y += a[q] * bfhi(w[q]);
    }
  }
  for (; k < deg; k++) {
    float a0 = exs[wid][k] * inv;
    unsigned w0 = *(const unsigned*)&hp[(size_t)(srcs[wid][k] + c)];
    acc.x += a0 * bflo(w0); acc.y += a0 * bfhi(w0);
  }
  acc.x = fmaxf(acc.x + bias[c], 0.f);
  acc.y = fmaxf(acc.y + bias[c + 1], 0.f);
  unsigned o = (unsigned)f2bf(acc.x) | ((unsigned)f2bf(acc.y) << 16);
  *(unsigned*)&hout[(size_t)node * DD + c] = o;
}

__global__ void pool_kernel(const unsigned short* __restrict__ h, float* __restrict__ g, int n) {
  __shared__ float sh[128];
  int tid = threadIdx.x;
  int cp = tid & 63, half = tid >> 6;     // 4 row-groups, lane owns 2 cols
  float sx = 0.f, sy = 0.f;
  for (int r = blockIdx.x * 4 + half; r < n; r += gridDim.x * 4) {
    unsigned w = *(const unsigned*)&h[(size_t)r * DD + cp * 2];
    sx += bflo(w); sy += bfhi(w);
  }
  if (half == 0) { sh[cp * 2] = sx; sh[cp * 2 + 1] = sy; }
  __syncthreads();
  if (half == 1) { sh[cp * 2] += sx; sh[cp * 2 + 1] += sy; }
  __syncthreads();
  if (half == 2) { sh[cp * 2] += sx; sh[cp * 2 + 1] += sy; }
  __syncthreads();
  if (half == 3) {
    atomicAdd(&g[cp * 2], sh[cp * 2] + sx);
    atomicAdd(&g[cp * 2 + 1], sh[cp * 2 + 1] + sy);
  }
}

__global__ void readout_kernel(const float* __restrict__ g, const float* __restrict__ Wr1,
                               const float* __restrict__ br1, const float* __restrict__ Wr2,
                               const float* __restrict__ br2, float* __restrict__ out,
                               float inv_n) {
  __shared__ float gl[128];
  __shared__ float m[64];
  int t = threadIdx.x;  // 64 threads
  gl[t] = g[t] * inv_n;
  gl[t + 64] = g[t + 64] * inv_n;
  __syncthreads();
  {
    float acc = br1[t];
    for (int c = 0; c < 128; c++) acc += gl[c] * Wr1[c * 64 + t];
    m[t] = fmaxf(acc, 0.f);
  }
  __syncthreads();
  if (t < 32) {
    float acc = br2[t];
    for (int j = 0; j < 64; j++) acc += m[j] * Wr2[j * 32 + t];
    out[t] = acc;
  }
}

// ---------------- launch ----------------
extern "C" void kernel_launch(void* const* d_in, const int* in_sizes, int n_in,
                              void* d_out, int out_size, void* d_ws, size_t ws_size,
                              hipStream_t stream) {
  const float* x     = (const float*)d_in[0];
  const int*   ei    = (const int*)d_in[1];
  const int*   eattr = (const int*)d_in[2];
  const float* W1 = (const float*)d_in[3];
  const float* b1 = (const float*)d_in[4];
  const float* W2 = (const float*)d_in[5];
  const float* b2 = (const float*)d_in[6];
  const float* rel_emb = (const float*)d_in[7];
  const float* lin[2]      = {(const float*)d_in[8],  (const float*)d_in[14]};
  const float* att_src[2]  = {(const float*)d_in[9],  (const float*)d_in[15]};
  const float* att_dst[2]  = {(const float*)d_in[10], (const float*)d_in[16]};
  const float* att_edge[2] = {(const float*)d_in[11], (const float*)d_in[17]};
  const float* line[2]     = {(const float*)d_in[12], (const float*)d_in[18]};
  const float* bias[2]     = {(const float*)d_in[13], (const float*)d_in[19]};
  const float* Wr1 = (const float*)d_in[20];
  const float* br1 = (const float*)d_in[21];
  const float* Wr2 = (const float*)d_in[22];
  const float* br2 = (const float*)d_in[23];
  float* out = (float*)d_out;

  const int* srcv = ei;
  const int* dstv = ei + EE;

  char* wsb = (char*)d_ws;
  unsigned short* hA  = (unsigned short*)(wsb + 0);
  unsigned short* hp  = (unsigned short*)(wsb + 12900000);
  unsigned short* hB  = (unsigned short*)(wsb + 25900000);
  unsigned short* mid = (unsigned short*)(wsb + 38800000);
  unsigned short* W1T   = (unsigned short*)(wsb + 64600000);
  unsigned short* W2L1T = (unsigned short*)(wsb + 64900000);   // [128][256] bf16
  unsigned short* lin2T = (unsigned short*)(wsb + 65040000);
  int* cnt     = (int*)(wsb + 65300008);                       // [50000]
  float* ssrc  = (float*)(wsb + 68100008);
  float* sdst  = (float*)(wsb + 68300008);
  float* tables = (float*)(wsb + 68502056);   // [2][32]
  float* g      = (float*)(wsb + 68502312);   // 128 f32
  float* b2l1   = (float*)(wsb + 68502824);   // 128 f32
  int* cpack    = (int*)(wsb + 70000000);     // [50000][64] = 12.8 MB

  dim3 blk(256);

  // prep: weight transposes + tables + W2L1 + zero cnt/g  (966 blocks)
  prep_kernel<<<dim3(966), blk, 0, stream>>>(
      W1, W2, lin[0], lin[1], line[0], line[1], att_edge[0], att_edge[1],
      rel_emb, b2, W1T, W2L1T, lin2T, tables, b2l1, cnt, g);
  gemm1_fused<<<dim3(782, 2), blk, 0, stream>>>(x, W1T, b1, mid);

  // bucketed CSR build (one kernel; replaces counting-sort chain)
  bucket_kernel<<<dim3((EE + 255) / 256), blk, 0, stream>>>(srcv, dstv, eattr, cnt, cpack, EE);

  // layer 1: hp = mid @ W2L1 + b2l1 (gemm2+lin1 fused) + DOTS -> gather -> hB
  gemm_mfma<true, false, true, true><<<dim3(391, 1), blk, 0, stream>>>(
      mid, W2L1T, b2l1, hp, NN, 128, 256, att_src[0], att_dst[0], ssrc, sdst);
  gat_gather_kernel<<<dim3((NN * 64 + 255) / 256), blk, 0, stream>>>(
      cnt, cpack, tables, ssrc, sdst, hp, bias[0], hB, NN);
  // layer 2: hB -> (lin2+DOTS) hp,ssrc,sdst -> (gather) hA
  gemm_mfma<true, false, false, true><<<dim3(391, 1), blk, 0, stream>>>(
      hB, lin2T, nullptr, hp, NN, 128, 128, att_src[1], att_dst[1], ssrc, sdst);
  gat_gather_kernel<<<dim3((NN * 64 + 255) / 256), blk, 0, stream>>>(
      cnt, cpack, tables + 32, ssrc, sdst, hp, bias[1], hA, NN);

  pool_kernel<<<dim3(256), blk, 0, stream>>>(hA, g, NN);
  readout_kernel<<<1, 64, 0, stream>>>(g, Wr1, br1, Wr2, br2, out, 1.0f / NN);
}

// Round 22
// 230.624 us; speedup vs baseline: 1.4642x; 1.0055x over previous
//
#include <hip/hip_runtime.h>
#include <hip/hip_bf16.h>

#define NN   50000
#define EE   600000
#define DINK 518
#define KP1  576          // padded K for encoder GEMM1 (9*64)
#define MP   50048        // padded rows (391*128)
#define DD   128
#define NEG_SLOPE 0.2f
#define CAP  64           // bucket capacity per node (deg ~ Poisson(12); P(>64)~1e-24)

typedef short bf16x8 __attribute__((ext_vector_type(8)));
typedef float f32x4 __attribute__((ext_vector_type(4)));

typedef const __attribute__((address_space(1))) void* gp1_t;
typedef __attribute__((address_space(3))) void* lp3_t;

__device__ __forceinline__ void load_lds16(const void* g, void* l) {
  __builtin_amdgcn_global_load_lds((gp1_t)g, (lp3_t)l, 16, 0, 0);
}

__device__ __forceinline__ unsigned short f2bf(float f) {
  union { float f; unsigned u; } q; q.f = f;
  unsigned u = q.u + 0x7FFFu + ((q.u >> 16) & 1u);   // RNE
  return (unsigned short)(u >> 16);
}
__device__ __forceinline__ float bflo(unsigned u) {
  union { unsigned u; float f; } q; q.u = u << 16; return q.f;
}
__device__ __forceinline__ float bfhi(unsigned u) {
  union { unsigned u; float f; } q; q.u = u & 0xFFFF0000u; return q.f;
}

// ---------------- bf16 MFMA GEMM:  C = act(A @ BT^T [+ bias]) ----------------
// A:[Mpad][K] bf16 row-major; BT:[Ncols][K] bf16. 128x128 tile, BK=64, 4 waves.
// DOTS (bn==0, Ncols==128): also emit ssrc/sdst = (C row).att_{src,dst}
// from the fp32 accumulators (+bias when HASBIAS) — replaces sdots kernel.
template<bool OUT_BF16, bool RELU, bool HASBIAS, bool DOTS>
__global__ __launch_bounds__(256) void gemm_mfma(
    const unsigned short* __restrict__ A, const unsigned short* __restrict__ BT,
    const float* __restrict__ bias, void* __restrict__ Cout,
    int M, int Ncols, int K,
    const float* __restrict__ att_src, const float* __restrict__ att_dst,
    float* __restrict__ ssrc, float* __restrict__ sdst) {
  __shared__ short As[128][64];
  __shared__ short Bs[128][64];
  __shared__ float sp[128], dp[128];
  const int tid = threadIdx.x;
  const int lane = tid & 63;
  const int wid = tid >> 6;
  const int wr = wid >> 1, wc = wid & 1;
  const int bm = blockIdx.x * 128;
  const int bn = blockIdx.y * 128;
  const int ar = tid >> 3;
  const int ac = (tid & 7) * 8;

  f32x4 acc[4][4] = {};

  for (int k0 = 0; k0 < K; k0 += 64) {
#pragma unroll
    for (int i = 0; i < 4; i++)
      load_lds16(A + (size_t)(bm + ar + i * 32) * K + k0 + ac, &As[ar + i * 32][ac]);
#pragma unroll
    for (int i = 0; i < 4; i++)
      load_lds16(BT + (size_t)(bn + ar + i * 32) * K + k0 + ac, &Bs[ar + i * 32][ac]);
    __syncthreads();
#pragma unroll
    for (int ks = 0; ks < 2; ks++) {
      bf16x8 af[4], bfm[4];
#pragma unroll
      for (int f = 0; f < 4; f++)
        af[f] = *(const bf16x8*)&As[wr * 64 + f * 16 + (lane & 15)][ks * 32 + (lane >> 4) * 8];
#pragma unroll
      for (int f = 0; f < 4; f++)
        bfm[f] = *(const bf16x8*)&Bs[wc * 64 + f * 16 + (lane & 15)][ks * 32 + (lane >> 4) * 8];
#pragma unroll
      for (int i = 0; i < 4; i++)
#pragma unroll
        for (int j = 0; j < 4; j++)
          acc[i][j] = __builtin_amdgcn_mfma_f32_16x16x32_bf16(af[i], bfm[j], acc[i][j], 0, 0, 0);
    }
    __syncthreads();
  }

  // C/D layout (m89/m91): col = lane&15, row = (lane>>4)*4 + reg
  const int col0 = bn + wc * 64 + (lane & 15);
  const int row0 = bm + wr * 64 + (lane >> 4) * 4;
#pragma unroll
  for (int i = 0; i < 4; i++) {
#pragma unroll
    for (int jf = 0; jf < 4; jf++) {
      int col = col0 + jf * 16;
      float bv = HASBIAS ? bias[col] : 0.f;
#pragma unroll
      for (int j = 0; j < 4; j++) {
        int row = row0 + i * 16 + j;
        if (row < M) {
          float v = acc[i][jf][j] + bv;
          if (RELU) v = fmaxf(v, 0.f);
          if (OUT_BF16)
            ((unsigned short*)Cout)[(size_t)row * Ncols + col] = f2bf(v);
          else
            ((float*)Cout)[(size_t)row * Ncols + col] = v;
        }
      }
    }
  }

  if (DOTS) {
    float as_[4], ad_[4], bv_[4];
#pragma unroll
    for (int jf = 0; jf < 4; jf++) {
      int col = col0 + jf * 16;           // bn==0, covers 0..127 across wc
      as_[jf] = att_src[col];
      ad_[jf] = att_dst[col];
      bv_[jf] = HASBIAS ? bias[col] : 0.f;
    }
    float ps[4][4], pd[4][4];
#pragma unroll
    for (int i = 0; i < 4; i++) {
#pragma unroll
      for (int j = 0; j < 4; j++) {
        float s = 0.f, d = 0.f;
#pragma unroll
        for (int jf = 0; jf < 4; jf++) {
          float vv = acc[i][jf][j] + bv_[jf];
          s += vv * as_[jf];
          d += vv * ad_[jf];
        }
#pragma unroll
        for (int off = 1; off < 16; off <<= 1) {   // butterfly over lane&15 (cols)
          s += __shfl_xor(s, off);
          d += __shfl_xor(d, off);
        }
        ps[i][j] = s; pd[i][j] = d;
      }
    }
    // cross-wave (wc) combine via LDS; local row = wr*64 + i*16 + (lane>>4)*4 + j
    if (wc == 0 && (lane & 15) == 0) {
#pragma unroll
      for (int i = 0; i < 4; i++)
#pragma unroll
        for (int j = 0; j < 4; j++) {
          int r = wr * 64 + i * 16 + (lane >> 4) * 4 + j;
          sp[r] = ps[i][j]; dp[r] = pd[i][j];
        }
    }
    __syncthreads();
    if (wc == 1 && (lane & 15) == 0) {
#pragma unroll
      for (int i = 0; i < 4; i++)
#pragma unroll
        for (int j = 0; j < 4; j++) {
          int r = wr * 64 + i * 16 + (lane >> 4) * 4 + j;
          sp[r] += ps[i][j]; dp[r] += pd[i][j];
        }
    }
    __syncthreads();
    if (tid < 128) {
      int gr = bm + tid;
      if (gr < M) { ssrc[gr] = sp[tid]; sdst[gr] = dp[tid]; }
    }
  }
}

// ---------------- GEMM1 with fused fp32->bf16 A conversion ----------------
// Round-13 proven config (72us, 35% occ): BM=64/BN=128, two-phase staging.
__global__ __launch_bounds__(256) void gemm1_fused(
    const float* __restrict__ x, const unsigned short* __restrict__ BT,
    const float* __restrict__ bias, unsigned short* __restrict__ Cout) {
  __shared__ short As[64][64];
  __shared__ short Bs[128][64];
  const int tid = threadIdx.x;
  const int lane = tid & 63;
  const int wid = tid >> 6;             // wave id = column-tile owner
  const int bm = blockIdx.x * 64;
  const int bn = blockIdx.y * 128;
  const int br = tid >> 3;              // B loader row 0..31
  const int bc = (tid & 7) * 8;
  const int rlane = lane >> 5;          // 0/1: which of the 2 rows per instr
  const int klane = (lane & 31) * 2;    // k-offset 0..62

  f32x4 acc[4][2] = {};

  for (int k0 = 0; k0 < KP1; k0 += 64) {
#pragma unroll
    for (int i = 0; i < 4; i++)
      load_lds16(BT + (size_t)(bn + br + i * 32) * KP1 + k0 + bc, &Bs[br + i * 32][bc]);
    // phase 1: issue all A loads (statically indexed -> registers)
    float2 v[8];
    const int kk = k0 + klane;
    const bool kok = (kk < DINK);
#pragma unroll
    for (int i = 0; i < 8; i++) {
      int grow = bm + wid * 16 + i * 2 + rlane;
      v[i] = make_float2(0.f, 0.f);
      if (kok && grow < NN) v[i] = *(const float2*)&x[(size_t)grow * DINK + kk];
    }
    // phase 2: convert + LDS write
#pragma unroll
    for (int i = 0; i < 8; i++) {
      int rl = wid * 16 + i * 2 + rlane;
      unsigned pk;
      asm("v_cvt_pk_bf16_f32 %0, %1, %2" : "=v"(pk) : "v"(v[i].x), "v"(v[i].y));
      *(unsigned*)&As[rl][klane] = pk;
    }
    __syncthreads();
#pragma unroll
    for (int ks = 0; ks < 2; ks++) {
      bf16x8 af[4], bfm[2];
#pragma unroll
      for (int f = 0; f < 4; f++)
        af[f] = *(const bf16x8*)&As[f * 16 + (lane & 15)][ks * 32 + (lane >> 4) * 8];
#pragma unroll
      for (int f = 0; f < 2; f++)
        bfm[f] = *(const bf16x8*)&Bs[wid * 32 + f * 16 + (lane & 15)][ks * 32 + (lane >> 4) * 8];
#pragma unroll
      for (int i = 0; i < 4; i++)
#pragma unroll
        for (int j = 0; j < 2; j++)
          acc[i][j] = __builtin_amdgcn_mfma_f32_16x16x32_bf16(af[i], bfm[j], acc[i][j], 0, 0, 0);
    }
    __syncthreads();
  }

  const int col0 = bn + wid * 32 + (lane & 15);
  const int row0 = bm + (lane >> 4) * 4;
#pragma unroll
  for (int i = 0; i < 4; i++) {
#pragma unroll
    for (int jf = 0; jf < 2; jf++) {
      int col = col0 + jf * 16;
      float bv = bias[col];
#pragma unroll
      for (int j = 0; j < 4; j++) {
        int row = row0 + i * 16 + j;
        if (row < NN) {
          float v2 = fmaxf(acc[i][jf][j] + bv, 0.f);
          Cout[(size_t)row * 256 + col] = f2bf(v2);
        }
      }
    }
  }
}

// -------- combined weight prep: W1T, l2T, tables, W2L1 = W2@lin1, and -------
// -------- zeroing of cnt (bucket counters) + g (pool accumulator) -----------
__device__ __forceinline__ void convT_body(const float* __restrict__ W,
                                           unsigned short* __restrict__ WT,
                                           int K, int Ncols, int Kpad, int t) {
  int n = t / Kpad, k = t % Kpad;
  float v = (k < K) ? W[(size_t)k * Ncols + n] : 0.f;
  WT[(size_t)n * Kpad + k] = f2bf(v);
}

__global__ __launch_bounds__(256) void prep_kernel(
    const float* __restrict__ W1, const float* __restrict__ W2,
    const float* __restrict__ l1, const float* __restrict__ l2,
    const float* __restrict__ le1, const float* __restrict__ le2,
    const float* __restrict__ ae1, const float* __restrict__ ae2,
    const float* __restrict__ rel_emb, const float* __restrict__ b2,
    unsigned short* __restrict__ W1T, unsigned short* __restrict__ W2L1T,
    unsigned short* __restrict__ l2T, float* __restrict__ tables,
    float* __restrict__ b2l1, int* __restrict__ cnt, float* __restrict__ g) {
  const int b = blockIdx.x, tid = threadIdx.x;
  if (b < 576) { convT_body(W1, W1T, DINK, 256, KP1, b * 256 + tid); return; }
  if (b < 640) { convT_body(l2, l2T, 128, 128, 128, (b - 576) * 256 + tid); return; }
  if (b < 642) {
    // tables[layer][r] = rel_emb[r] . (line @ att_edge)
    const int layer = b - 640;
    const float* line = layer ? le2 : le1;
    const float* ae   = layer ? ae2 : ae1;
    __shared__ float ve[32];
    if (tid < 32) {
      float s = 0.f;
      for (int d = 0; d < 128; d++) s += line[tid * 128 + d] * ae[d];
      ve[tid] = s;
    }
    __syncthreads();
    if (tid < 26) {
      float s = 0.f;
      for (int j = 0; j < 32; j++) s += rel_emb[tid * 32 + j] * ve[j];
      tables[layer * 32 + tid] = s;
    }
    return;
  }
  if (b < 770) {
    // W2L1T[n][k] = sum_j W2[k][j]*lin1[j][n]  (n = output col, k = 0..255)
    const int n = b - 642;
    __shared__ float lc[128];
    if (tid < 128) lc[tid] = l1[(size_t)tid * 128 + n];
    __syncthreads();
    float s = 0.f;
    const float* wrow = W2 + (size_t)tid * 128;
    for (int j = 0; j < 128; j++) s += wrow[j] * lc[j];
    W2L1T[(size_t)n * 256 + tid] = f2bf(s);
    if (tid == 0) {
      float bb = 0.f;
      for (int j = 0; j < 128; j++) bb += b2[j] * lc[j];
      b2l1[n] = bb;
    }
    return;
  }
  // b in [770, 966): zero cnt[50000]; block 770 also zeros g[128]
  {
    const int zb = b - 770;
    int i = zb * 256 + tid;
    if (i < NN) cnt[i] = 0;
    if (zb == 0 && tid < 128) g[tid] = 0.f;
  }
}

// ------- bucket build: cpack[node*CAP + p] = (src<<5)|attr; cnt = degree ----
__global__ void bucket_kernel(const int* __restrict__ src, const int* __restrict__ dst,
                              const int* __restrict__ attr, int* __restrict__ cnt,
                              int* __restrict__ cpack, int E) {
  int e = blockIdx.x * blockDim.x + threadIdx.x;
  if (e >= E) return;
  int d = dst[e];
  int p = atomicAdd(&cnt[d], 1);
  if (p < CAP) cpack[d * CAP + p] = (src[e] << 5) | attr[e];
}

// ---------------- fused GAT aggregate: TWO NODES PER WAVE -------------------
// lanes 0-31 own node A, 32-63 node B; each lane owns 4 cols (8B uint2/row —
// same gathered bytes in half the load instructions; wave count halves).
// Shuffle reduce uses offsets 16..1 (never crosses the half boundary).
__global__ __launch_bounds__(256) void gat_gather_kernel(
    const int* __restrict__ cnt, const int* __restrict__ cpack,
    const float* __restrict__ table,
    const float* __restrict__ ssrc, const float* __restrict__ sdst,
    const unsigned short* __restrict__ hp, const float* __restrict__ bias,
    unsigned short* __restrict__ hout, int n) {
  __shared__ float exs[4][2][CAP];
  __shared__ int   srcs[4][2][CAP];
  const int wid = threadIdx.x >> 6, lane = threadIdx.x & 63;
  const int half = lane >> 5, hlane = lane & 31;
  const int node = ((blockIdx.x * blockDim.x + threadIdx.x) >> 6) * 2 + half;
  const bool valid = node < n;
  int deg = valid ? cnt[node] : 0;
  if (deg > CAP) deg = CAP;   // impossible for this graph; guards OOB
  const int j0 = node * CAP;
  const float sd = valid ? sdst[node] : 0.f;
  float den = 0.f, esum = 0.f;
  for (int k = hlane; k < deg; k += 32) {   // deg <= 64: at most 2 steps
    int pk_ = cpack[j0 + k];
    int s = pk_ >> 5;
    float t = table[pk_ & 31];
    float l = ssrc[s] + sd + t;
    l = (l > 0.f) ? l : NEG_SLOPE * l;
    float ex = expf(l);
    exs[wid][half][k] = ex; srcs[wid][half][k] = s * DD;
    den += ex; esum += t;
  }
#pragma unroll
  for (int off = 16; off; off >>= 1) {   // within-half butterfly
    den += __shfl_xor(den, off);
    esum += __shfl_xor(esum, off);
  }
  // self-loop (edge vector = mean of incoming -> table-space mean)
  float tl = esum / fmaxf((float)deg, 1.f);
  float ll = (valid ? ssrc[node] : 0.f) + sd + tl;
  ll = (ll > 0.f) ? ll : NEG_SLOPE * ll;
  float exl = expf(ll);
  den += exl;
  const float inv = 1.f / (den + 1e-16f);
  // pass 2: lane owns cols c..c+3 (one 8B uint2 of bf16 per row)
  const int c = hlane * 4;
  float a0, a1, a2, a3;
  {
    uint2 w = valid ? *(const uint2*)&hp[(size_t)node * DD + c] : make_uint2(0, 0);
    float a = exl * inv;
    a0 = a * bflo(w.x); a1 = a * bfhi(w.x);
    a2 = a * bflo(w.y); a3 = a * bfhi(w.y);
  }
  int k = 0;
  for (; k + 8 <= deg; k += 8) {
    uint2 w[8]; float a[8];
#pragma unroll
    for (int q = 0; q < 8; q++) {
      a[q] = exs[wid][half][k + q] * inv;
      w[q] = *(const uint2*)&hp[(size_t)(srcs[wid][half][k + q] + c)];
    }
#pragma unroll
    for (int q = 0; q < 8; q++) {
      a0 += a[q] * bflo(w[q].x); a1 += a[q] * bfhi(w[q].x);
      a2 += a[q] * bflo(w[q].y); a3 += a[q] * bfhi(w[q].y);
    }
  }
  for (; k + 4 <= deg; k += 4) {
    uint2 w[4]; float a[4];
#pragma unroll
    for (int q = 0; q < 4; q++) {
      a[q] = exs[wid][half][k + q] * inv;
      w[q] = *(const uint2*)&hp[(size_t)(srcs[wid][half][k + q] + c)];
    }
#pragma unroll
    for (int q = 0; q < 4; q++) {
      a0 += a[q] * bflo(w[q].x); a1 += a[q] * bfhi(w[q].x);
      a2 += a[q] * bflo(w[q].y); a3 += a[q] * bfhi(w[q].y);
    }
  }
  for (; k < deg; k++) {
    float aq = exs[wid][half][k] * inv;
    uint2 w = *(const uint2*)&hp[(size_t)(srcs[wid][half][k] + c)];
    a0 += aq * bflo(w.x); a1 += aq * bfhi(w.x);
    a2 += aq * bflo(w.y); a3 += aq * bfhi(w.y);
  }
  if (valid) {
    a0 = fmaxf(a0 + bias[c], 0.f);
    a1 = fmaxf(a1 + bias[c + 1], 0.f);
    a2 = fmaxf(a2 + bias[c + 2], 0.f);
    a3 = fmaxf(a3 + bias[c + 3], 0.f);
    uint2 o;
    o.x = (unsigned)f2bf(a0) | ((unsigned)f2bf(a1) << 16);
    o.y = (unsigned)f2bf(a2) | ((unsigned)f2bf(a3) << 16);
    *(uint2*)&hout[(size_t)node * DD + c] = o;
  }
}

__global__ void pool_kernel(const unsigned short* __restrict__ h, float* __restrict__ g, int n) {
  __shared__ float sh[128];
  int tid = threadIdx.x;
  int cp = tid & 63, half = tid >> 6;     // 4 row-groups, lane owns 2 cols
  float sx = 0.f, sy = 0.f;
  for (int r = blockIdx.x * 4 + half; r < n; r += gridDim.x * 4) {
    unsigned w = *(const unsigned*)&h[(size_t)r * DD + cp * 2];
    sx += bflo(w); sy += bfhi(w);
  }
  if (half == 0) { sh[cp * 2] = sx; sh[cp * 2 + 1] = sy; }
  __syncthreads();
  if (half == 1) { sh[cp * 2] += sx; sh[cp * 2 + 1] += sy; }
  __syncthreads();
  if (half == 2) { sh[cp * 2] += sx; sh[cp * 2 + 1] += sy; }
  __syncthreads();
  if (half == 3) {
    atomicAdd(&g[cp * 2], sh[cp * 2] + sx);
    atomicAdd(&g[cp * 2 + 1], sh[cp * 2 + 1] + sy);
  }
}

__global__ void readout_kernel(const float* __restrict__ g, const float* __restrict__ Wr1,
                               const float* __restrict__ br1, const float* __restrict__ Wr2,
                               const float* __restrict__ br2, float* __restrict__ out,
                               float inv_n) {
  __shared__ float gl[128];
  __shared__ float m[64];
  int t = threadIdx.x;  // 64 threads
  gl[t] = g[t] * inv_n;
  gl[t + 64] = g[t + 64] * inv_n;
  __syncthreads();
  {
    float acc = br1[t];
    for (int c = 0; c < 128; c++) acc += gl[c] * Wr1[c * 64 + t];
    m[t] = fmaxf(acc, 0.f);
  }
  __syncthreads();
  if (t < 32) {
    float acc = br2[t];
    for (int j = 0; j < 64; j++) acc += m[j] * Wr2[j * 32 + t];
    out[t] = acc;
  }
}

// ---------------- launch ----------------
extern "C" void kernel_launch(void* const* d_in, const int* in_sizes, int n_in,
                              void* d_out, int out_size, void* d_ws, size_t ws_size,
                              hipStream_t stream) {
  const float* x     = (const float*)d_in[0];
  const int*   ei    = (const int*)d_in[1];
  const int*   eattr = (const int*)d_in[2];
  const float* W1 = (const float*)d_in[3];
  const float* b1 = (const float*)d_in[4];
  const float* W2 = (const float*)d_in[5];
  const float* b2 = (const float*)d_in[6];
  const float* rel_emb = (const float*)d_in[7];
  const float* lin[2]      = {(const float*)d_in[8],  (const float*)d_in[14]};
  const float* att_src[2]  = {(const float*)d_in[9],  (const float*)d_in[15]};
  const float* att_dst[2]  = {(const float*)d_in[10], (const float*)d_in[16]};
  const float* att_edge[2] = {(const float*)d_in[11], (const float*)d_in[17]};
  const float* line[2]     = {(const float*)d_in[12], (const float*)d_in[18]};
  const float* bias[2]     = {(const float*)d_in[13], (const float*)d_in[19]};
  const float* Wr1 = (const float*)d_in[20];
  const float* br1 = (const float*)d_in[21];
  const float* Wr2 = (const float*)d_in[22];
  const float* br2 = (const float*)d_in[23];
  float* out = (float*)d_out;

  const int* srcv = ei;
  const int* dstv = ei + EE;

  char* wsb = (char*)d_ws;
  unsigned short* hA  = (unsigned short*)(wsb + 0);
  unsigned short* hp  = (unsigned short*)(wsb + 12900000);
  unsigned short* hB  = (unsigned short*)(wsb + 25900000);
  unsigned short* mid = (unsigned short*)(wsb + 38800000);
  unsigned short* W1T   = (unsigned short*)(wsb + 64600000);
  unsigned short* W2L1T = (unsigned short*)(wsb + 64900000);   // [128][256] bf16
  unsigned short* lin2T = (unsigned short*)(wsb + 65040000);
  int* cnt     = (int*)(wsb + 65300008);                       // [50000]
  float* ssrc  = (float*)(wsb + 68100008);
  float* sdst  = (float*)(wsb + 68300008);
  float* tables = (float*)(wsb + 68502056);   // [2][32]
  float* g      = (float*)(wsb + 68502312);   // 128 f32
  float* b2l1   = (float*)(wsb + 68502824);   // 128 f32
  int* cpack    = (int*)(wsb + 70000000);     // [50000][64] = 12.8 MB

  dim3 blk(256);

  // prep: weight transposes + tables + W2L1 + zero cnt/g  (966 blocks)
  prep_kernel<<<dim3(966), blk, 0, stream>>>(
      W1, W2, lin[0], lin[1], line[0], line[1], att_edge[0], att_edge[1],
      rel_emb, b2, W1T, W2L1T, lin2T, tables, b2l1, cnt, g);
  gemm1_fused<<<dim3(782, 2), blk, 0, stream>>>(x, W1T, b1, mid);

  // bucketed CSR build (one kernel)
  bucket_kernel<<<dim3((EE + 255) / 256), blk, 0, stream>>>(srcv, dstv, eattr, cnt, cpack, EE);

  // layer 1: hp = mid @ W2L1 + b2l1 (gemm2+lin1 fused) + DOTS -> gather -> hB
  gemm_mfma<true, false, true, true><<<dim3(391, 1), blk, 0, stream>>>(
      mid, W2L1T, b2l1, hp, NN, 128, 256, att_src[0], att_dst[0], ssrc, sdst);
  gat_gather_kernel<<<dim3((NN / 2 * 64 + 255) / 256), blk, 0, stream>>>(
      cnt, cpack, tables, ssrc, sdst, hp, bias[0], hB, NN);
  // layer 2: hB -> (lin2+DOTS) hp,ssrc,sdst -> (gather) hA
  gemm_mfma<true, false, false, true><<<dim3(391, 1), blk, 0, stream>>>(
      hB, lin2T, nullptr, hp, NN, 128, 128, att_src[1], att_dst[1], ssrc, sdst);
  gat_gather_kernel<<<dim3((NN / 2 * 64 + 255) / 256), blk, 0, stream>>>(
      cnt, cpack, tables + 32, ssrc, sdst, hp, bias[1], hA, NN);

  pool_kernel<<<dim3(256), blk, 0, stream>>>(hA, g, NN);
  readout_kernel<<<1, 64, 0, stream>>>(g, Wr1, br1, Wr2, br2, out, 1.0f / NN);
}